// Round 3
// baseline (1069.557 us; speedup 1.0000x reference)
//
#include <hip/hip_runtime.h>

#define N_NODES  50000
#define N_EDGES  600000
#define DIM      128
#define N_GRAPHS 128
#define N_CLASSES 10

// NOTE: harness delivers ALL integer inputs as int32 (const int*), regardless
// of the reference's int64 dtype. Reading them as long long was an OOB fault.

// ---------------- utility: zero a region ----------------

__global__ __launch_bounds__(256) void k_zero(float* __restrict__ p, int n) {
  int i = blockIdx.x * 256 + threadIdx.x;
  if (i < n) p[i] = 0.f;
}

// ---------------- CSR build ----------------

__global__ __launch_bounds__(256) void k_deg(const int* __restrict__ ei,
                                             int* __restrict__ deg) {
  int e = blockIdx.x * 256 + threadIdx.x;
  if (e < N_EDGES) {
    int d = ei[N_EDGES + e];   // dst row of edge_index
    atomicAdd(&deg[d], 1);
  }
}

__global__ __launch_bounds__(256) void k_dinv(const int* __restrict__ deg,
                                              float* __restrict__ dinv) {
  int n = blockIdx.x * 256 + threadIdx.x;
  if (n < N_NODES) {
    int d = deg[n];
    dinv[n] = (d > 0) ? rsqrtf((float)d) : 0.f;
  }
}

// single-block exclusive scan of deg -> rowp (N+1 entries)
__global__ __launch_bounds__(1024) void k_scan(const int* __restrict__ deg,
                                               int* __restrict__ rowp) {
  const int CH = (N_NODES + 1023) / 1024;  // 49
  int t = threadIdx.x;
  int start = t * CH;
  int end = start + CH; if (end > N_NODES) end = N_NODES;
  int s = 0;
  for (int i = start; i < end; ++i) s += deg[i];
  __shared__ int tmp[1024];
  tmp[t] = s;
  __syncthreads();
  for (int off = 1; off < 1024; off <<= 1) {
    int v = (t >= off) ? tmp[t - off] : 0;
    __syncthreads();
    tmp[t] += v;
    __syncthreads();
  }
  int run = (t > 0) ? tmp[t - 1] : 0;   // exclusive prefix for this chunk
  for (int i = start; i < end; ++i) { rowp[i] = run; run += deg[i]; }
  if (t == 1023) rowp[N_NODES] = run;   // == N_EDGES
}

__global__ __launch_bounds__(256) void k_fill(const int* __restrict__ ei,
                                              const int* __restrict__ rowp,
                                              int* __restrict__ cnt,
                                              const float* __restrict__ dinv,
                                              int* __restrict__ csrc,
                                              float* __restrict__ enorm) {
  int e = blockIdx.x * 256 + threadIdx.x;
  if (e < N_EDGES) {
    int s = ei[e];
    int d = ei[N_EDGES + e];
    int p = rowp[d] + atomicAdd(&cnt[d], 1);
    csrc[p] = s;
    enorm[p] = dinv[s] * dinv[d];
  }
}

// ---------------- fused dual GEMM: hw = x@W ; xout = x@R + b ----------------
// block: 256 threads, tile 64 rows x (128 W-cols + 128 R-cols)
// thread: 32 rows x (1 W-col + 1 R-col); LDS x-tile broadcast reads.
// NOTE: block b reads ONLY rows [64b,64b+64) of xin (staged to LDS before any
// global write) and writes the same rows of hw/xout -> xin==xout is safe.

__global__ __launch_bounds__(256) void k_gemm(const float* __restrict__ xin,
                                              const float* __restrict__ W,
                                              const float* __restrict__ R,
                                              const float* __restrict__ b,
                                              float* __restrict__ hw,
                                              float* __restrict__ xout) {
  __shared__ float xs[64][DIM];
  const int tid = threadIdx.x;
  const int row0 = blockIdx.x * 64;
  // stage 64x128 fp32 as float4, coalesced
#pragma unroll
  for (int i = 0; i < 8; ++i) {
    int idx = i * 256 + tid;          // float4 index 0..2047
    int r = idx >> 5, k4 = idx & 31;
    int row = row0 + r;
    float4 v = make_float4(0.f, 0.f, 0.f, 0.f);
    if (row < N_NODES) v = *(const float4*)&xin[row * DIM + k4 * 4];
    *(float4*)&xs[r][k4 * 4] = v;
  }
  __syncthreads();
  const int c = tid & 127;
  const int rg = tid >> 7;            // row group 0/1 (wave-uniform)
  float accw[32], accr[32];
#pragma unroll
  for (int r = 0; r < 32; ++r) { accw[r] = 0.f; accr[r] = 0.f; }
  for (int k0 = 0; k0 < DIM; k0 += 4) {
    float w0 = W[(k0 + 0) * DIM + c], w1 = W[(k0 + 1) * DIM + c];
    float w2 = W[(k0 + 2) * DIM + c], w3 = W[(k0 + 3) * DIM + c];
    float r0 = R[(k0 + 0) * DIM + c], r1 = R[(k0 + 1) * DIM + c];
    float r2 = R[(k0 + 2) * DIM + c], r3 = R[(k0 + 3) * DIM + c];
#pragma unroll
    for (int r = 0; r < 32; ++r) {
      float4 xv = *(const float4*)&xs[rg * 32 + r][k0];   // broadcast, conflict-free
      accw[r] = fmaf(xv.x, w0, fmaf(xv.y, w1, fmaf(xv.z, w2, fmaf(xv.w, w3, accw[r]))));
      accr[r] = fmaf(xv.x, r0, fmaf(xv.y, r1, fmaf(xv.z, r2, fmaf(xv.w, r3, accr[r]))));
    }
  }
  float bias = b[c];
#pragma unroll
  for (int r = 0; r < 32; ++r) {
    int row = row0 + rg * 32 + r;
    if (row < N_NODES) {
      hw[row * DIM + c] = accw[r];
      xout[row * DIM + c] = accr[r] + bias;
    }
  }
}

// ---------------- aggregation: xout[n] += sum_e norm*hw[src]; relu ----------------
// one wave per dst node; lane holds 2 dims (float2)

__global__ __launch_bounds__(256) void k_agg(const float* __restrict__ hw,
                                             const int* __restrict__ rowp,
                                             const int* __restrict__ csrc,
                                             const float* __restrict__ enorm,
                                             float* __restrict__ xout) {
  int n = blockIdx.x * 4 + (threadIdx.x >> 6);
  if (n >= N_NODES) return;
  int lane = threadIdx.x & 63;
  float2 acc = *(const float2*)&xout[n * DIM + lane * 2];
  int e0 = rowp[n], e1 = rowp[n + 1];
  for (int e = e0; e < e1; ++e) {
    int s = csrc[e];
    float w = enorm[e];
    float2 v = *(const float2*)&hw[s * DIM + lane * 2];
    acc.x = fmaf(w, v.x, acc.x);
    acc.y = fmaf(w, v.y, acc.y);
  }
  acc.x = fmaxf(acc.x, 0.f);
  acc.y = fmaxf(acc.y, 0.f);
  *(float2*)&xout[n * DIM + lane * 2] = acc;
}

// ---------------- global mean pool (atomics) ----------------

__global__ __launch_bounds__(256) void k_pool(const float* __restrict__ h,
                                              const int* __restrict__ batch,
                                              float* __restrict__ psum,
                                              float* __restrict__ pcnt) {
  int n = blockIdx.x * 4 + (threadIdx.x >> 6);
  if (n >= N_NODES) return;
  int lane = threadIdx.x & 63;
  int g = batch[n];
  float2 v = *(const float2*)&h[n * DIM + lane * 2];
  atomicAdd(&psum[g * DIM + lane * 2], v.x);
  atomicAdd(&psum[g * DIM + lane * 2 + 1], v.y);
  if (lane == 0) atomicAdd(&pcnt[g], 1.f);
}

// ---------------- MLP head ----------------

__global__ __launch_bounds__(128) void k_mlp1(const float* __restrict__ psum,
                                              const float* __restrict__ pcnt,
                                              const float* __restrict__ w,
                                              const float* __restrict__ bias,
                                              float* __restrict__ g1) {
  int g = blockIdx.x, t = threadIdx.x;
  __shared__ float sp[DIM];
  float c = fmaxf(pcnt[g], 1.f);
  sp[t] = psum[g * DIM + t] / c;
  __syncthreads();
  float acc = bias[t];
#pragma unroll 4
  for (int k = 0; k < DIM; ++k) acc = fmaf(sp[k], w[k * DIM + t], acc);
  g1[g * DIM + t] = fmaxf(acc, 0.f);
}

__global__ __launch_bounds__(128) void k_mlp2(const float* __restrict__ g1,
                                              const float* __restrict__ w,
                                              const float* __restrict__ bias,
                                              float* __restrict__ out) {
  int g = threadIdx.x;   // one thread per graph
  float l[N_CLASSES];
#pragma unroll
  for (int c = 0; c < N_CLASSES; ++c) l[c] = bias[c];
  for (int k = 0; k < DIM; ++k) {
    float gv = g1[g * DIM + k];
#pragma unroll
    for (int c = 0; c < N_CLASSES; ++c) l[c] = fmaf(gv, w[k * N_CLASSES + c], l[c]);
  }
  float m = l[0];
#pragma unroll
  for (int c = 1; c < N_CLASSES; ++c) m = fmaxf(m, l[c]);
  float s = 0.f;
#pragma unroll
  for (int c = 0; c < N_CLASSES; ++c) s += expf(l[c] - m);
  float lse = logf(s) + m;
#pragma unroll
  for (int c = 0; c < N_CLASSES; ++c) out[g * N_CLASSES + c] = l[c] - lse;
}

// ---------------- launch ----------------

extern "C" void kernel_launch(void* const* d_in, const int* in_sizes, int n_in,
                              void* d_out, int out_size, void* d_ws, size_t ws_size,
                              hipStream_t stream) {
  const float* x     = (const float*)d_in[0];
  const int* ei      = (const int*)d_in[1];     // int32 on device (harness)
  const int* batch   = (const int*)d_in[2];     // int32 on device (harness)
  const float* W1  = (const float*)d_in[3];
  const float* R1  = (const float*)d_in[4];
  const float* b1  = (const float*)d_in[5];
  const float* Wc  = (const float*)d_in[6];
  const float* Rc  = (const float*)d_in[7];
  const float* bc  = (const float*)d_in[8];
  const float* l1w = (const float*)d_in[9];
  const float* l1b = (const float*)d_in[10];
  const float* l2w = (const float*)d_in[11];
  const float* l2b = (const float*)d_in[12];

  float* out   = (float*)d_out;
  float* dlast = out + N_GRAPHS * N_CLASSES;   // 'last' region; doubles as the
                                               // layer feature buffer (in-place)

  // ---- workspace layout (floats), total 7,832,912 f = 31.33 MB ----
  float* ws    = (float*)d_ws;
  float* hw    = ws;                        // 6,400,000
  int*   deg   = (int*)(ws + 6400000);      // 50,000
  int*   cnt   = (int*)(ws + 6450000);      // 50,000
  float* psum  = ws + 6500000;              // 16,384
  float* pcnt  = ws + 6516384;              // 128
  float* dinv  = ws + 6516512;              // 50,000
  int*   rowp  = (int*)(ws + 6566512);      // 50,001 (padded to 50,016)
  int*   csrc  = (int*)(ws + 6616528);      // 600,000
  float* enorm = ws + 7216528;              // 600,000
  float* g1    = ws + 7816528;              // 16,384

  // zero deg+cnt+psum+pcnt (contiguous block of 116,512 words)
  k_zero<<<(116512 + 255) / 256, 256, 0, stream>>>(ws + 6400000, 116512);

  k_deg <<<(N_EDGES + 255) / 256, 256, 0, stream>>>(ei, deg);
  k_dinv<<<(N_NODES + 255) / 256, 256, 0, stream>>>(deg, dinv);
  k_scan<<<1, 1024, 0, stream>>>(deg, rowp);
  k_fill<<<(N_EDGES + 255) / 256, 256, 0, stream>>>(ei, rowp, cnt, dinv, csrc, enorm);

  const float* xin = x;
  for (int l = 0; l < 4; ++l) {
    const float* W = (l == 0) ? W1 : Wc + (size_t)(l - 1) * DIM * DIM;
    const float* R = (l == 0) ? R1 : Rc + (size_t)(l - 1) * DIM * DIM;
    const float* B = (l == 0) ? b1 : bc + (size_t)(l - 1) * DIM;
    k_gemm<<<(N_NODES + 63) / 64, 256, 0, stream>>>(xin, W, R, B, hw, dlast);
    k_agg <<<(N_NODES + 3) / 4, 256, 0, stream>>>(hw, rowp, csrc, enorm, dlast);
    xin = dlast;
  }

  k_pool<<<(N_NODES + 3) / 4, 256, 0, stream>>>(dlast, batch, psum, pcnt);
  k_mlp1<<<N_GRAPHS, 128, 0, stream>>>(psum, pcnt, l1w, l1b, g1);
  k_mlp2<<<1, N_GRAPHS, 0, stream>>>(g1, l2w, l2b, out);
}

// Round 4
// 835.135 us; speedup vs baseline: 1.2807x; 1.2807x over previous
//
#include <hip/hip_runtime.h>

#define N_NODES  50000
#define N_EDGES  600000
#define DIM      128
#define N_GRAPHS 128
#define N_CLASSES 10

// NOTE: harness delivers ALL integer inputs as int32 (const int*), regardless
// of the reference's int64 dtype. Reading them as long long was an OOB fault.

// ---------------- utility: zero a region ----------------

__global__ __launch_bounds__(256) void k_zero(float* __restrict__ p, int n) {
  int i = blockIdx.x * 256 + threadIdx.x;
  if (i < n) p[i] = 0.f;
}

// ---------------- CSR build ----------------

__global__ __launch_bounds__(256) void k_deg(const int* __restrict__ ei,
                                             int* __restrict__ deg) {
  int e = blockIdx.x * 256 + threadIdx.x;
  if (e < N_EDGES) {
    int d = ei[N_EDGES + e];   // dst row of edge_index
    atomicAdd(&deg[d], 1);
  }
}

__global__ __launch_bounds__(256) void k_dinv(const int* __restrict__ deg,
                                              float* __restrict__ dinv) {
  int n = blockIdx.x * 256 + threadIdx.x;
  if (n < N_NODES) {
    int d = deg[n];
    dinv[n] = (d > 0) ? rsqrtf((float)d) : 0.f;
  }
}

// single-block exclusive scan of deg -> rowp (N+1 entries)
__global__ __launch_bounds__(1024) void k_scan(const int* __restrict__ deg,
                                               int* __restrict__ rowp) {
  const int CH = (N_NODES + 1023) / 1024;  // 49
  int t = threadIdx.x;
  int start = t * CH;
  int end = start + CH; if (end > N_NODES) end = N_NODES;
  int s = 0;
  for (int i = start; i < end; ++i) s += deg[i];
  __shared__ int tmp[1024];
  tmp[t] = s;
  __syncthreads();
  for (int off = 1; off < 1024; off <<= 1) {
    int v = (t >= off) ? tmp[t - off] : 0;
    __syncthreads();
    tmp[t] += v;
    __syncthreads();
  }
  int run = (t > 0) ? tmp[t - 1] : 0;   // exclusive prefix for this chunk
  for (int i = start; i < end; ++i) { rowp[i] = run; run += deg[i]; }
  if (t == 1023) rowp[N_NODES] = run;   // == N_EDGES
}

__global__ __launch_bounds__(256) void k_fill(const int* __restrict__ ei,
                                              const int* __restrict__ rowp,
                                              int* __restrict__ cnt,
                                              const float* __restrict__ dinv,
                                              int* __restrict__ csrc,
                                              float* __restrict__ enorm) {
  int e = blockIdx.x * 256 + threadIdx.x;
  if (e < N_EDGES) {
    int s = ei[e];
    int d = ei[N_EDGES + e];
    int p = rowp[d] + atomicAdd(&cnt[d], 1);
    csrc[p] = s;
    enorm[p] = dinv[s] * dinv[d];
  }
}

// ---------------- fused dual GEMM: hw = x@W ; xout = x@R + b ----------------
// block: 256 threads, tile 64 rows x (128 W-cols + 128 R-cols)
// thread: 32 rows x (1 W-col + 1 R-col); LDS x-tile broadcast reads.
// NOTE: block b reads ONLY rows [64b,64b+64) of xin (staged to LDS before any
// global write) and writes the same rows of hw/xout -> xin==xout is safe.

__global__ __launch_bounds__(256) void k_gemm(const float* __restrict__ xin,
                                              const float* __restrict__ W,
                                              const float* __restrict__ R,
                                              const float* __restrict__ b,
                                              float* __restrict__ hw,
                                              float* __restrict__ xout) {
  __shared__ float xs[64][DIM];
  const int tid = threadIdx.x;
  const int row0 = blockIdx.x * 64;
  // stage 64x128 fp32 as float4, coalesced
#pragma unroll
  for (int i = 0; i < 8; ++i) {
    int idx = i * 256 + tid;          // float4 index 0..2047
    int r = idx >> 5, k4 = idx & 31;
    int row = row0 + r;
    float4 v = make_float4(0.f, 0.f, 0.f, 0.f);
    if (row < N_NODES) v = *(const float4*)&xin[row * DIM + k4 * 4];
    *(float4*)&xs[r][k4 * 4] = v;
  }
  __syncthreads();
  const int c = tid & 127;
  const int rg = tid >> 7;            // row group 0/1 (wave-uniform)
  float accw[32], accr[32];
#pragma unroll
  for (int r = 0; r < 32; ++r) { accw[r] = 0.f; accr[r] = 0.f; }
  for (int k0 = 0; k0 < DIM; k0 += 4) {
    float w0 = W[(k0 + 0) * DIM + c], w1 = W[(k0 + 1) * DIM + c];
    float w2 = W[(k0 + 2) * DIM + c], w3 = W[(k0 + 3) * DIM + c];
    float r0 = R[(k0 + 0) * DIM + c], r1 = R[(k0 + 1) * DIM + c];
    float r2 = R[(k0 + 2) * DIM + c], r3 = R[(k0 + 3) * DIM + c];
#pragma unroll
    for (int r = 0; r < 32; ++r) {
      float4 xv = *(const float4*)&xs[rg * 32 + r][k0];   // broadcast, conflict-free
      accw[r] = fmaf(xv.x, w0, fmaf(xv.y, w1, fmaf(xv.z, w2, fmaf(xv.w, w3, accw[r]))));
      accr[r] = fmaf(xv.x, r0, fmaf(xv.y, r1, fmaf(xv.z, r2, fmaf(xv.w, r3, accr[r]))));
    }
  }
  float bias = b[c];
#pragma unroll
  for (int r = 0; r < 32; ++r) {
    int row = row0 + rg * 32 + r;
    if (row < N_NODES) {
      hw[row * DIM + c] = accw[r];
      xout[row * DIM + c] = accr[r] + bias;
    }
  }
}

// ---------------- aggregation: xout[n] += sum_e norm*hw[src]; relu ----------------
// one wave per dst node; lane holds 2 dims (float2)

__global__ __launch_bounds__(256) void k_agg(const float* __restrict__ hw,
                                             const int* __restrict__ rowp,
                                             const int* __restrict__ csrc,
                                             const float* __restrict__ enorm,
                                             float* __restrict__ xout) {
  int n = blockIdx.x * 4 + (threadIdx.x >> 6);
  if (n >= N_NODES) return;
  int lane = threadIdx.x & 63;
  float2 acc = *(const float2*)&xout[n * DIM + lane * 2];
  int e0 = rowp[n], e1 = rowp[n + 1];
  for (int e = e0; e < e1; ++e) {
    int s = csrc[e];
    float w = enorm[e];
    float2 v = *(const float2*)&hw[s * DIM + lane * 2];
    acc.x = fmaf(w, v.x, acc.x);
    acc.y = fmaf(w, v.y, acc.y);
  }
  acc.x = fmaxf(acc.x, 0.f);
  acc.y = fmaxf(acc.y, 0.f);
  *(float2*)&xout[n * DIM + lane * 2] = acc;
}

// ---------------- global mean pool: block per graph, batch is SORTED ----------------
// binary-search graph boundaries, 8-way row-parallel sum, LDS reduce, no atomics

__global__ __launch_bounds__(1024) void k_pool2(const float* __restrict__ h,
                                                const int* __restrict__ batch,
                                                float* __restrict__ pooled) {
  int g = blockIdx.x;
  int t = threadIdx.x;
  __shared__ int sb[2];
  if (t < 2) {
    int target = g + t;                 // lower_bound(batch, target)
    int lo = 0, hi = N_NODES;
    while (lo < hi) {
      int mid = (lo + hi) >> 1;
      if (batch[mid] < target) lo = mid + 1; else hi = mid;
    }
    sb[t] = lo;
  }
  __syncthreads();
  int start = sb[0], end = sb[1];
  int c = t & 127, rg = t >> 7;         // 8 row groups
  float acc = 0.f;
  for (int r = start + rg; r < end; r += 8) acc += h[r * DIM + c];
  __shared__ float sp[8][DIM];
  sp[rg][c] = acc;
  __syncthreads();
  if (rg == 0) {
    float tot = acc;
#pragma unroll
    for (int i = 1; i < 8; ++i) tot += sp[i][c];
    float cnt = fmaxf((float)(end - start), 1.f);
    pooled[g * DIM + c] = tot / cnt;
  }
}

// ---------------- MLP head ----------------

__global__ __launch_bounds__(128) void k_mlp1(const float* __restrict__ pooled,
                                              const float* __restrict__ w,
                                              const float* __restrict__ bias,
                                              float* __restrict__ g1) {
  int g = blockIdx.x, t = threadIdx.x;
  __shared__ float sp[DIM];
  sp[t] = pooled[g * DIM + t];
  __syncthreads();
  float acc = bias[t];
#pragma unroll 4
  for (int k = 0; k < DIM; ++k) acc = fmaf(sp[k], w[k * DIM + t], acc);
  g1[g * DIM + t] = fmaxf(acc, 0.f);
}

__global__ __launch_bounds__(128) void k_mlp2(const float* __restrict__ g1,
                                              const float* __restrict__ w,
                                              const float* __restrict__ bias,
                                              float* __restrict__ out) {
  int g = threadIdx.x;   // one thread per graph
  float l[N_CLASSES];
#pragma unroll
  for (int c = 0; c < N_CLASSES; ++c) l[c] = bias[c];
  for (int k = 0; k < DIM; ++k) {
    float gv = g1[g * DIM + k];
#pragma unroll
    for (int c = 0; c < N_CLASSES; ++c) l[c] = fmaf(gv, w[k * N_CLASSES + c], l[c]);
  }
  float m = l[0];
#pragma unroll
  for (int c = 1; c < N_CLASSES; ++c) m = fmaxf(m, l[c]);
  float s = 0.f;
#pragma unroll
  for (int c = 0; c < N_CLASSES; ++c) s += expf(l[c] - m);
  float lse = logf(s) + m;
#pragma unroll
  for (int c = 0; c < N_CLASSES; ++c) out[g * N_CLASSES + c] = l[c] - lse;
}

// ---------------- launch ----------------

extern "C" void kernel_launch(void* const* d_in, const int* in_sizes, int n_in,
                              void* d_out, int out_size, void* d_ws, size_t ws_size,
                              hipStream_t stream) {
  const float* x     = (const float*)d_in[0];
  const int* ei      = (const int*)d_in[1];     // int32 on device (harness)
  const int* batch   = (const int*)d_in[2];     // int32 on device (harness)
  const float* W1  = (const float*)d_in[3];
  const float* R1  = (const float*)d_in[4];
  const float* b1  = (const float*)d_in[5];
  const float* Wc  = (const float*)d_in[6];
  const float* Rc  = (const float*)d_in[7];
  const float* bc  = (const float*)d_in[8];
  const float* l1w = (const float*)d_in[9];
  const float* l1b = (const float*)d_in[10];
  const float* l2w = (const float*)d_in[11];
  const float* l2b = (const float*)d_in[12];

  float* out   = (float*)d_out;
  float* dlast = out + N_GRAPHS * N_CLASSES;   // 'last' region; doubles as the
                                               // layer feature buffer (in-place)

  // ---- workspace layout (floats), total ~31.3 MB ----
  float* ws    = (float*)d_ws;
  float* hw    = ws;                        // 6,400,000
  int*   deg   = (int*)(ws + 6400000);      // 50,000
  int*   cnt   = (int*)(ws + 6450000);      // 50,000
  float* pooled= ws + 6500000;              // 16,384
  float* dinv  = ws + 6516512;              // 50,000
  int*   rowp  = (int*)(ws + 6566512);      // 50,001 (padded to 50,016)
  int*   csrc  = (int*)(ws + 6616528);      // 600,000
  float* enorm = ws + 7216528;              // 600,000
  float* g1    = ws + 7816528;              // 16,384

  // zero deg+cnt (contiguous block of 100,000 words)
  k_zero<<<(100000 + 255) / 256, 256, 0, stream>>>(ws + 6400000, 100000);

  k_deg <<<(N_EDGES + 255) / 256, 256, 0, stream>>>(ei, deg);
  k_dinv<<<(N_NODES + 255) / 256, 256, 0, stream>>>(deg, dinv);
  k_scan<<<1, 1024, 0, stream>>>(deg, rowp);
  k_fill<<<(N_EDGES + 255) / 256, 256, 0, stream>>>(ei, rowp, cnt, dinv, csrc, enorm);

  const float* xin = x;
  for (int l = 0; l < 4; ++l) {
    const float* W = (l == 0) ? W1 : Wc + (size_t)(l - 1) * DIM * DIM;
    const float* R = (l == 0) ? R1 : Rc + (size_t)(l - 1) * DIM * DIM;
    const float* B = (l == 0) ? b1 : bc + (size_t)(l - 1) * DIM;
    k_gemm<<<(N_NODES + 63) / 64, 256, 0, stream>>>(xin, W, R, B, hw, dlast);
    k_agg <<<(N_NODES + 3) / 4, 256, 0, stream>>>(hw, rowp, csrc, enorm, dlast);
    xin = dlast;
  }

  k_pool2<<<N_GRAPHS, 1024, 0, stream>>>(dlast, batch, pooled);
  k_mlp1<<<N_GRAPHS, 128, 0, stream>>>(pooled, l1w, l1b, g1);
  k_mlp2<<<1, N_GRAPHS, 0, stream>>>(g1, l2w, l2b, out);
}

// Round 5
// 790.919 us; speedup vs baseline: 1.3523x; 1.0559x over previous
//
#include <hip/hip_runtime.h>

#define N_NODES  50000
#define N_EDGES  600000
#define DIM      128
#define N_GRAPHS 128
#define N_CLASSES 10

// NOTE: harness delivers ALL integer inputs as int32 (const int*).

// ---------------- utility: zero a region ----------------

__global__ __launch_bounds__(256) void k_zero(float* __restrict__ p, int n) {
  int i = blockIdx.x * 256 + threadIdx.x;
  if (i < n) p[i] = 0.f;
}

// ---------------- CSR build ----------------

__global__ __launch_bounds__(256) void k_deg(const int* __restrict__ ei,
                                             int* __restrict__ deg) {
  int e = blockIdx.x * 256 + threadIdx.x;
  if (e < N_EDGES) {
    int d = ei[N_EDGES + e];   // dst row of edge_index
    atomicAdd(&deg[d], 1);
  }
}

__global__ __launch_bounds__(256) void k_dinv(const int* __restrict__ deg,
                                              float* __restrict__ dinv) {
  int n = blockIdx.x * 256 + threadIdx.x;
  if (n < N_NODES) {
    int d = deg[n];
    dinv[n] = (d > 0) ? rsqrtf((float)d) : 0.f;
  }
}

// single-block exclusive scan of deg -> rowp (N+1 entries)
__global__ __launch_bounds__(1024) void k_scan(const int* __restrict__ deg,
                                               int* __restrict__ rowp) {
  const int CH = (N_NODES + 1023) / 1024;  // 49
  int t = threadIdx.x;
  int start = t * CH;
  int end = start + CH; if (end > N_NODES) end = N_NODES;
  int s = 0;
  for (int i = start; i < end; ++i) s += deg[i];
  __shared__ int tmp[1024];
  tmp[t] = s;
  __syncthreads();
  for (int off = 1; off < 1024; off <<= 1) {
    int v = (t >= off) ? tmp[t - off] : 0;
    __syncthreads();
    tmp[t] += v;
    __syncthreads();
  }
  int run = (t > 0) ? tmp[t - 1] : 0;   // exclusive prefix for this chunk
  for (int i = start; i < end; ++i) { rowp[i] = run; run += deg[i]; }
  if (t == 1023) rowp[N_NODES] = run;   // == N_EDGES
}

__global__ __launch_bounds__(256) void k_fill(const int* __restrict__ ei,
                                              const int* __restrict__ rowp,
                                              int* __restrict__ cnt,
                                              const float* __restrict__ dinv,
                                              int* __restrict__ csrc,
                                              float* __restrict__ enorm) {
  int e = blockIdx.x * 256 + threadIdx.x;
  if (e < N_EDGES) {
    int s = ei[e];
    int d = ei[N_EDGES + e];
    int p = rowp[d] + atomicAdd(&cnt[d], 1);
    csrc[p] = s;
    enorm[p] = dinv[s] * dinv[d];
  }
}

// ---------------- fused dual GEMM: hw = x@W ; xout = x@R + b ----------------
// 1024 threads, tile 64 rows x (128 W-cols ++ 128 R-cols).
// thread: 16 rows x 1 col -> 16 accumulators, ALL in VGPRs (the R4 kernel's
// accw[32]+accr[32] forced AGPR round-trips: VGPR_Count=48, VALUBusy 47%).
// Weight loads software-pipelined (wnext) to cover L2 latency.
// In-place safe: block b reads only rows [64b,64b+64) of xin (staged to LDS
// before any global write) and writes the same rows.

__global__ __launch_bounds__(1024) void k_gemm(const float* __restrict__ xin,
                                               const float* __restrict__ W,
                                               const float* __restrict__ R,
                                               const float* __restrict__ b,
                                               float* __restrict__ hw,
                                               float* __restrict__ xout) {
  __shared__ float xs[64][DIM];
  const int tid = threadIdx.x;
  const int row0 = blockIdx.x * 64;
  // stage 64x128 fp32 as float4, coalesced: 2048 float4 / 1024 threads
#pragma unroll
  for (int i = 0; i < 2; ++i) {
    int idx = i * 1024 + tid;
    int r = idx >> 5, k4 = idx & 31;
    int row = row0 + r;
    float4 v = make_float4(0.f, 0.f, 0.f, 0.f);
    if (row < N_NODES) v = *(const float4*)&xin[row * DIM + k4 * 4];
    *(float4*)&xs[r][k4 * 4] = v;
  }
  __syncthreads();
  const int c    = tid & 127;          // output column
  const int path = (tid >> 7) & 1;     // 0 -> W/hw, 1 -> R/xout (wave-uniform)
  const int rg   = tid >> 8;           // row group 0..3 (wave-uniform)
  const float* __restrict__ M = path ? R : W;

  float acc[16];
#pragma unroll
  for (int r = 0; r < 16; ++r) acc[r] = 0.f;

  float4 wcur, wnext;
  wcur.x = M[0 * DIM + c]; wcur.y = M[1 * DIM + c];
  wcur.z = M[2 * DIM + c]; wcur.w = M[3 * DIM + c];
  for (int k0 = 0; k0 < DIM - 4; k0 += 4) {
    wnext.x = M[(k0 + 4) * DIM + c]; wnext.y = M[(k0 + 5) * DIM + c];
    wnext.z = M[(k0 + 6) * DIM + c]; wnext.w = M[(k0 + 7) * DIM + c];
#pragma unroll
    for (int r = 0; r < 16; ++r) {
      float4 xv = *(const float4*)&xs[rg * 16 + r][k0];   // LDS broadcast
      acc[r] = fmaf(xv.x, wcur.x, fmaf(xv.y, wcur.y,
               fmaf(xv.z, wcur.z, fmaf(xv.w, wcur.w, acc[r]))));
    }
    wcur = wnext;
  }
#pragma unroll
  for (int r = 0; r < 16; ++r) {        // last K chunk (k0 = 124)
    float4 xv = *(const float4*)&xs[rg * 16 + r][DIM - 4];
    acc[r] = fmaf(xv.x, wcur.x, fmaf(xv.y, wcur.y,
             fmaf(xv.z, wcur.z, fmaf(xv.w, wcur.w, acc[r]))));
  }

  if (path == 0) {
#pragma unroll
    for (int r = 0; r < 16; ++r) {
      int row = row0 + rg * 16 + r;
      if (row < N_NODES) hw[row * DIM + c] = acc[r];
    }
  } else {
    float bias = b[c];
#pragma unroll
    for (int r = 0; r < 16; ++r) {
      int row = row0 + rg * 16 + r;
      if (row < N_NODES) xout[row * DIM + c] = acc[r] + bias;
    }
  }
}

// ---------------- aggregation: xout[n] += sum_e norm*hw[src]; relu ----------------
// half-wave (32 lanes) per dst node, lane holds 4 dims (float4); 2-edge unroll

__global__ __launch_bounds__(256) void k_agg(const float* __restrict__ hw,
                                             const int* __restrict__ rowp,
                                             const int* __restrict__ csrc,
                                             const float* __restrict__ enorm,
                                             float* __restrict__ xout) {
  int n = blockIdx.x * 8 + (threadIdx.x >> 5);
  if (n >= N_NODES) return;
  int l4 = (threadIdx.x & 31) * 4;
  float4 acc = *(const float4*)&xout[n * DIM + l4];
  int e = rowp[n], e1 = rowp[n + 1];
  for (; e + 2 <= e1; e += 2) {
    int s0 = csrc[e],  s1 = csrc[e + 1];
    float w0 = enorm[e], w1 = enorm[e + 1];
    float4 v0 = *(const float4*)&hw[s0 * DIM + l4];
    float4 v1 = *(const float4*)&hw[s1 * DIM + l4];
    acc.x = fmaf(w0, v0.x, fmaf(w1, v1.x, acc.x));
    acc.y = fmaf(w0, v0.y, fmaf(w1, v1.y, acc.y));
    acc.z = fmaf(w0, v0.z, fmaf(w1, v1.z, acc.z));
    acc.w = fmaf(w0, v0.w, fmaf(w1, v1.w, acc.w));
  }
  if (e < e1) {
    int s0 = csrc[e];
    float w0 = enorm[e];
    float4 v0 = *(const float4*)&hw[s0 * DIM + l4];
    acc.x = fmaf(w0, v0.x, acc.x);
    acc.y = fmaf(w0, v0.y, acc.y);
    acc.z = fmaf(w0, v0.z, acc.z);
    acc.w = fmaf(w0, v0.w, acc.w);
  }
  acc.x = fmaxf(acc.x, 0.f);
  acc.y = fmaxf(acc.y, 0.f);
  acc.z = fmaxf(acc.z, 0.f);
  acc.w = fmaxf(acc.w, 0.f);
  *(float4*)&xout[n * DIM + l4] = acc;
}

// ---------------- global mean pool: block per graph, batch is SORTED ----------------

__global__ __launch_bounds__(1024) void k_pool2(const float* __restrict__ h,
                                                const int* __restrict__ batch,
                                                float* __restrict__ pooled) {
  int g = blockIdx.x;
  int t = threadIdx.x;
  __shared__ int sb[2];
  if (t < 2) {
    int target = g + t;                 // lower_bound(batch, target)
    int lo = 0, hi = N_NODES;
    while (lo < hi) {
      int mid = (lo + hi) >> 1;
      if (batch[mid] < target) lo = mid + 1; else hi = mid;
    }
    sb[t] = lo;
  }
  __syncthreads();
  int start = sb[0], end = sb[1];
  int c = t & 127, rg = t >> 7;         // 8 row groups
  float acc = 0.f;
  for (int r = start + rg; r < end; r += 8) acc += h[r * DIM + c];
  __shared__ float sp[8][DIM];
  sp[rg][c] = acc;
  __syncthreads();
  if (rg == 0) {
    float tot = acc;
#pragma unroll
    for (int i = 1; i < 8; ++i) tot += sp[i][c];
    float cnt = fmaxf((float)(end - start), 1.f);
    pooled[g * DIM + c] = tot / cnt;
  }
}

// ---------------- MLP head ----------------

__global__ __launch_bounds__(128) void k_mlp1(const float* __restrict__ pooled,
                                              const float* __restrict__ w,
                                              const float* __restrict__ bias,
                                              float* __restrict__ g1) {
  int g = blockIdx.x, t = threadIdx.x;
  __shared__ float sp[DIM];
  sp[t] = pooled[g * DIM + t];
  __syncthreads();
  float acc = bias[t];
#pragma unroll 4
  for (int k = 0; k < DIM; ++k) acc = fmaf(sp[k], w[k * DIM + t], acc);
  g1[g * DIM + t] = fmaxf(acc, 0.f);
}

__global__ __launch_bounds__(128) void k_mlp2(const float* __restrict__ g1,
                                              const float* __restrict__ w,
                                              const float* __restrict__ bias,
                                              float* __restrict__ out) {
  int g = threadIdx.x;   // one thread per graph
  float l[N_CLASSES];
#pragma unroll
  for (int c = 0; c < N_CLASSES; ++c) l[c] = bias[c];
  for (int k = 0; k < DIM; ++k) {
    float gv = g1[g * DIM + k];
#pragma unroll
    for (int c = 0; c < N_CLASSES; ++c) l[c] = fmaf(gv, w[k * N_CLASSES + c], l[c]);
  }
  float m = l[0];
#pragma unroll
  for (int c = 1; c < N_CLASSES; ++c) m = fmaxf(m, l[c]);
  float s = 0.f;
#pragma unroll
  for (int c = 0; c < N_CLASSES; ++c) s += expf(l[c] - m);
  float lse = logf(s) + m;
#pragma unroll
  for (int c = 0; c < N_CLASSES; ++c) out[g * N_CLASSES + c] = l[c] - lse;
}

// ---------------- launch ----------------

extern "C" void kernel_launch(void* const* d_in, const int* in_sizes, int n_in,
                              void* d_out, int out_size, void* d_ws, size_t ws_size,
                              hipStream_t stream) {
  const float* x     = (const float*)d_in[0];
  const int* ei      = (const int*)d_in[1];     // int32 on device (harness)
  const int* batch   = (const int*)d_in[2];     // int32 on device (harness)
  const float* W1  = (const float*)d_in[3];
  const float* R1  = (const float*)d_in[4];
  const float* b1  = (const float*)d_in[5];
  const float* Wc  = (const float*)d_in[6];
  const float* Rc  = (const float*)d_in[7];
  const float* bc  = (const float*)d_in[8];
  const float* l1w = (const float*)d_in[9];
  const float* l1b = (const float*)d_in[10];
  const float* l2w = (const float*)d_in[11];
  const float* l2b = (const float*)d_in[12];

  float* out   = (float*)d_out;
  float* dlast = out + N_GRAPHS * N_CLASSES;   // 'last' region; doubles as the
                                               // layer feature buffer (in-place)

  // ---- workspace layout (floats), total ~31.3 MB ----
  float* ws    = (float*)d_ws;
  float* hw    = ws;                        // 6,400,000
  int*   deg   = (int*)(ws + 6400000);      // 50,000
  int*   cnt   = (int*)(ws + 6450000);      // 50,000
  float* pooled= ws + 6500000;              // 16,384
  float* dinv  = ws + 6516512;              // 50,000
  int*   rowp  = (int*)(ws + 6566512);      // 50,001 (padded to 50,016)
  int*   csrc  = (int*)(ws + 6616528);      // 600,000
  float* enorm = ws + 7216528;              // 600,000
  float* g1    = ws + 7816528;              // 16,384

  // zero deg+cnt (contiguous block of 100,000 words)
  k_zero<<<(100000 + 255) / 256, 256, 0, stream>>>(ws + 6400000, 100000);

  k_deg <<<(N_EDGES + 255) / 256, 256, 0, stream>>>(ei, deg);
  k_dinv<<<(N_NODES + 255) / 256, 256, 0, stream>>>(deg, dinv);
  k_scan<<<1, 1024, 0, stream>>>(deg, rowp);
  k_fill<<<(N_EDGES + 255) / 256, 256, 0, stream>>>(ei, rowp, cnt, dinv, csrc, enorm);

  const float* xin = x;
  for (int l = 0; l < 4; ++l) {
    const float* W = (l == 0) ? W1 : Wc + (size_t)(l - 1) * DIM * DIM;
    const float* R = (l == 0) ? R1 : Rc + (size_t)(l - 1) * DIM * DIM;
    const float* B = (l == 0) ? b1 : bc + (size_t)(l - 1) * DIM;
    k_gemm<<<(N_NODES + 63) / 64, 1024, 0, stream>>>(xin, W, R, B, hw, dlast);
    k_agg <<<(N_NODES + 7) / 8, 256, 0, stream>>>(hw, rowp, csrc, enorm, dlast);
    xin = dlast;
  }

  k_pool2<<<N_GRAPHS, 1024, 0, stream>>>(dlast, batch, pooled);
  k_mlp1<<<N_GRAPHS, 128, 0, stream>>>(pooled, l1w, l1b, g1);
  k_mlp2<<<1, N_GRAPHS, 0, stream>>>(g1, l2w, l2b, out);
}

// Round 6
// 663.651 us; speedup vs baseline: 1.6116x; 1.1918x over previous
//
#include <hip/hip_runtime.h>

#define N_NODES  50000
#define N_EDGES  600000
#define DIM      128
#define N_GRAPHS 128
#define N_CLASSES 10

// NOTE: harness delivers ALL integer inputs as int32 (const int*).

__device__ inline unsigned short f2bf(float f) {      // RNE float->bf16
  union { float f; unsigned int i; } u; u.f = f;
  unsigned int r = u.i + 0x7fff + ((u.i >> 16) & 1);
  return (unsigned short)(r >> 16);
}
__device__ inline float bf2f(unsigned short s) {
  union { unsigned int i; float f; } u; u.i = ((unsigned int)s) << 16;
  return u.f;
}

// ---------------- utility: zero a region ----------------

__global__ __launch_bounds__(256) void k_zero(float* __restrict__ p, int n) {
  int i = blockIdx.x * 256 + threadIdx.x;
  if (i < n) p[i] = 0.f;
}

// ---------------- weight transpose: k-chunk-major float4 ----------------
// wt[m*4096 + kc*128 + c] = float4(M[4kc..4kc+3][c]) for matrices
// m: 0=W1, 1..3=Wc[0..2], 4=R1, 5..7=Rc[0..2]

__global__ __launch_bounds__(256) void k_wt(const float* __restrict__ W1,
                                            const float* __restrict__ R1,
                                            const float* __restrict__ Wc,
                                            const float* __restrict__ Rc,
                                            float4* __restrict__ wt) {
  int m = blockIdx.y;
  const float* src = (m == 0) ? W1
                   : (m < 4)  ? Wc + (size_t)(m - 1) * DIM * DIM
                   : (m == 4) ? R1
                              : Rc + (size_t)(m - 5) * DIM * DIM;
  int idx = blockIdx.x * 256 + threadIdx.x;   // 0..4095
  int kc = idx >> 7, c = idx & 127;
  float4 v;
  v.x = src[(kc * 4 + 0) * DIM + c];
  v.y = src[(kc * 4 + 1) * DIM + c];
  v.z = src[(kc * 4 + 2) * DIM + c];
  v.w = src[(kc * 4 + 3) * DIM + c];
  wt[(size_t)m * 4096 + idx] = v;
}

// ---------------- CSR build ----------------

__global__ __launch_bounds__(256) void k_deg(const int* __restrict__ ei,
                                             int* __restrict__ deg) {
  int e = blockIdx.x * 256 + threadIdx.x;
  if (e < N_EDGES) atomicAdd(&deg[ei[N_EDGES + e]], 1);
}

__global__ __launch_bounds__(256) void k_dinv(const int* __restrict__ deg,
                                              float* __restrict__ dinv) {
  int n = blockIdx.x * 256 + threadIdx.x;
  if (n < N_NODES) {
    int d = deg[n];
    dinv[n] = (d > 0) ? rsqrtf((float)d) : 0.f;
  }
}

__global__ __launch_bounds__(1024) void k_scan(const int* __restrict__ deg,
                                               int* __restrict__ rowp) {
  const int CH = (N_NODES + 1023) / 1024;  // 49
  int t = threadIdx.x;
  int start = t * CH;
  int end = start + CH; if (end > N_NODES) end = N_NODES;
  int s = 0;
  for (int i = start; i < end; ++i) s += deg[i];
  __shared__ int tmp[1024];
  tmp[t] = s;
  __syncthreads();
  for (int off = 1; off < 1024; off <<= 1) {
    int v = (t >= off) ? tmp[t - off] : 0;
    __syncthreads();
    tmp[t] += v;
    __syncthreads();
  }
  int run = (t > 0) ? tmp[t - 1] : 0;
  for (int i = start; i < end; ++i) { rowp[i] = run; run += deg[i]; }
  if (t == 1023) rowp[N_NODES] = run;
}

__global__ __launch_bounds__(256) void k_fill(const int* __restrict__ ei,
                                              const int* __restrict__ rowp,
                                              int* __restrict__ cnt,
                                              const float* __restrict__ dinv,
                                              int* __restrict__ csrc,
                                              float* __restrict__ enorm) {
  int e = blockIdx.x * 256 + threadIdx.x;
  if (e < N_EDGES) {
    int s = ei[e];
    int d = ei[N_EDGES + e];
    int p = rowp[d] + atomicAdd(&cnt[d], 1);
    csrc[p] = s;
    enorm[p] = dinv[s] * dinv[d];
  }
}

// ---------------- fused dual GEMM: hwb = bf16(x@W) ; xout = x@R + b ----------------
// 1024 threads, 64-row tile. Thread = 8 rows x {W-col c, R-col c} -> 16 VGPR accs.
// Each LDS float4 read feeds 8 FMAs (R5's 1-path version was LDS-BW-bound at
// 94us: 8.4MB LDS reads/block = 6.6GB total ~ 95us at 69TB/s).
// Weights pre-transposed (k_wt) -> 2 global_load_dwordx4 per k-chunk, prefetched.
// In-place safe: block b stages rows [64b,64b+64) to LDS before writing them.

__global__ __launch_bounds__(1024, 2) void k_gemm(const float* __restrict__ xin,
                                                  const float4* __restrict__ Wt,
                                                  const float4* __restrict__ Rt,
                                                  const float* __restrict__ b,
                                                  unsigned short* __restrict__ hwb,
                                                  float* __restrict__ xout) {
  __shared__ float xs[64][DIM];
  const int tid = threadIdx.x;
  const int row0 = blockIdx.x * 64;
#pragma unroll
  for (int i = 0; i < 2; ++i) {
    int idx = i * 1024 + tid;
    int r = idx >> 5, k4 = idx & 31;
    int row = row0 + r;
    float4 v = make_float4(0.f, 0.f, 0.f, 0.f);
    if (row < N_NODES) v = *(const float4*)&xin[row * DIM + k4 * 4];
    *(float4*)&xs[r][k4 * 4] = v;
  }
  __syncthreads();
  const int c  = tid & 127;           // output column
  const int rg = tid >> 7;            // row group 0..7 (8 rows each)

  float accw[8], accr[8];
#pragma unroll
  for (int r = 0; r < 8; ++r) { accw[r] = 0.f; accr[r] = 0.f; }

  float4 wc = Wt[c], rc = Rt[c];
  for (int kc = 0; kc < 31; ++kc) {
    float4 wn = Wt[(kc + 1) * 128 + c];
    float4 rn = Rt[(kc + 1) * 128 + c];
#pragma unroll
    for (int r = 0; r < 8; ++r) {
      float4 xv = *(const float4*)&xs[rg * 8 + r][kc * 4];   // LDS broadcast
      accw[r] = fmaf(xv.x, wc.x, fmaf(xv.y, wc.y,
                fmaf(xv.z, wc.z, fmaf(xv.w, wc.w, accw[r]))));
      accr[r] = fmaf(xv.x, rc.x, fmaf(xv.y, rc.y,
                fmaf(xv.z, rc.z, fmaf(xv.w, rc.w, accr[r]))));
    }
    wc = wn; rc = rn;
  }
#pragma unroll
  for (int r = 0; r < 8; ++r) {        // last k-chunk (k = 124..127)
    float4 xv = *(const float4*)&xs[rg * 8 + r][124];
    accw[r] = fmaf(xv.x, wc.x, fmaf(xv.y, wc.y,
              fmaf(xv.z, wc.z, fmaf(xv.w, wc.w, accw[r]))));
    accr[r] = fmaf(xv.x, rc.x, fmaf(xv.y, rc.y,
              fmaf(xv.z, rc.z, fmaf(xv.w, rc.w, accr[r]))));
  }

  float bias = b[c];
#pragma unroll
  for (int r = 0; r < 8; ++r) {
    int row = row0 + rg * 8 + r;
    if (row < N_NODES) {
      hwb[row * DIM + c] = f2bf(accw[r]);
      xout[row * DIM + c] = accr[r] + bias;
    }
  }
}

// ---------------- aggregation: xout[n] += sum_e norm*hw[src]; relu ----------------
// half-wave (32 lanes) per dst node; lane holds 4 dims as bf16x4 (8B gathers)

__global__ __launch_bounds__(256) void k_agg(const unsigned short* __restrict__ hwb,
                                             const int* __restrict__ rowp,
                                             const int* __restrict__ csrc,
                                             const float* __restrict__ enorm,
                                             float* __restrict__ xout) {
  int n = blockIdx.x * 8 + (threadIdx.x >> 5);
  if (n >= N_NODES) return;
  int l4 = (threadIdx.x & 31) * 4;
  float4 acc = *(const float4*)&xout[n * DIM + l4];
  int e = rowp[n], e1 = rowp[n + 1];
  for (; e + 2 <= e1; e += 2) {
    int s0 = csrc[e],  s1 = csrc[e + 1];
    float w0 = enorm[e], w1 = enorm[e + 1];
    ushort4 u0 = *(const ushort4*)&hwb[s0 * DIM + l4];
    ushort4 u1 = *(const ushort4*)&hwb[s1 * DIM + l4];
    acc.x = fmaf(w0, bf2f(u0.x), fmaf(w1, bf2f(u1.x), acc.x));
    acc.y = fmaf(w0, bf2f(u0.y), fmaf(w1, bf2f(u1.y), acc.y));
    acc.z = fmaf(w0, bf2f(u0.z), fmaf(w1, bf2f(u1.z), acc.z));
    acc.w = fmaf(w0, bf2f(u0.w), fmaf(w1, bf2f(u1.w), acc.w));
  }
  if (e < e1) {
    int s0 = csrc[e];
    float w0 = enorm[e];
    ushort4 u0 = *(const ushort4*)&hwb[s0 * DIM + l4];
    acc.x = fmaf(w0, bf2f(u0.x), acc.x);
    acc.y = fmaf(w0, bf2f(u0.y), acc.y);
    acc.z = fmaf(w0, bf2f(u0.z), acc.z);
    acc.w = fmaf(w0, bf2f(u0.w), acc.w);
  }
  acc.x = fmaxf(acc.x, 0.f);
  acc.y = fmaxf(acc.y, 0.f);
  acc.z = fmaxf(acc.z, 0.f);
  acc.w = fmaxf(acc.w, 0.f);
  *(float4*)&xout[n * DIM + l4] = acc;
}

// ---------------- global mean pool: block per graph, batch is SORTED ----------------

__global__ __launch_bounds__(1024) void k_pool2(const float* __restrict__ h,
                                                const int* __restrict__ batch,
                                                float* __restrict__ pooled) {
  int g = blockIdx.x;
  int t = threadIdx.x;
  __shared__ int sb[2];
  if (t < 2) {
    int target = g + t;                 // lower_bound(batch, target)
    int lo = 0, hi = N_NODES;
    while (lo < hi) {
      int mid = (lo + hi) >> 1;
      if (batch[mid] < target) lo = mid + 1; else hi = mid;
    }
    sb[t] = lo;
  }
  __syncthreads();
  int start = sb[0], end = sb[1];
  int c = t & 127, rg = t >> 7;         // 8 row groups
  float acc = 0.f;
  for (int r = start + rg; r < end; r += 8) acc += h[r * DIM + c];
  __shared__ float sp[8][DIM];
  sp[rg][c] = acc;
  __syncthreads();
  if (rg == 0) {
    float tot = acc;
#pragma unroll
    for (int i = 1; i < 8; ++i) tot += sp[i][c];
    float cnt = fmaxf((float)(end - start), 1.f);
    pooled[g * DIM + c] = tot / cnt;
  }
}

// ---------------- MLP head ----------------

__global__ __launch_bounds__(128) void k_mlp1(const float* __restrict__ pooled,
                                              const float* __restrict__ w,
                                              const float* __restrict__ bias,
                                              float* __restrict__ g1) {
  int g = blockIdx.x, t = threadIdx.x;
  __shared__ float sp[DIM];
  sp[t] = pooled[g * DIM + t];
  __syncthreads();
  float acc = bias[t];
#pragma unroll 4
  for (int k = 0; k < DIM; ++k) acc = fmaf(sp[k], w[k * DIM + t], acc);
  g1[g * DIM + t] = fmaxf(acc, 0.f);
}

__global__ __launch_bounds__(128) void k_mlp2(const float* __restrict__ g1,
                                              const float* __restrict__ w,
                                              const float* __restrict__ bias,
                                              float* __restrict__ out) {
  int g = threadIdx.x;   // one thread per graph
  float l[N_CLASSES];
#pragma unroll
  for (int c = 0; c < N_CLASSES; ++c) l[c] = bias[c];
  for (int k = 0; k < DIM; ++k) {
    float gv = g1[g * DIM + k];
#pragma unroll
    for (int c = 0; c < N_CLASSES; ++c) l[c] = fmaf(gv, w[k * N_CLASSES + c], l[c]);
  }
  float m = l[0];
#pragma unroll
  for (int c = 1; c < N_CLASSES; ++c) m = fmaxf(m, l[c]);
  float s = 0.f;
#pragma unroll
  for (int c = 0; c < N_CLASSES; ++c) s += expf(l[c] - m);
  float lse = logf(s) + m;
#pragma unroll
  for (int c = 0; c < N_CLASSES; ++c) out[g * N_CLASSES + c] = l[c] - lse;
}

// ---------------- launch ----------------

extern "C" void kernel_launch(void* const* d_in, const int* in_sizes, int n_in,
                              void* d_out, int out_size, void* d_ws, size_t ws_size,
                              hipStream_t stream) {
  const float* x     = (const float*)d_in[0];
  const int* ei      = (const int*)d_in[1];     // int32 on device (harness)
  const int* batch   = (const int*)d_in[2];     // int32 on device (harness)
  const float* W1  = (const float*)d_in[3];
  const float* R1  = (const float*)d_in[4];
  const float* b1  = (const float*)d_in[5];
  const float* Wc  = (const float*)d_in[6];
  const float* Rc  = (const float*)d_in[7];
  const float* bc  = (const float*)d_in[8];
  const float* l1w = (const float*)d_in[9];
  const float* l1b = (const float*)d_in[10];
  const float* l2w = (const float*)d_in[11];
  const float* l2b = (const float*)d_in[12];

  float* out   = (float*)d_out;
  float* dlast = out + N_GRAPHS * N_CLASSES;   // 'last' region; in-place layer buffer

  // ---- workspace layout (float words), total 4,763,856 w = 19.1 MB ----
  float* ws    = (float*)d_ws;
  unsigned short* hwb = (unsigned short*)ws;    // 6,400,000 ushort = 3,200,000 w
  int*   deg   = (int*)(ws + 3200000);          // 50,000
  int*   cnt   = (int*)(ws + 3250000);          // 50,000
  float* pooled= ws + 3300000;                  // 16,384
  float* dinv  = ws + 3316384;                  // 50,000
  int*   rowp  = (int*)(ws + 3366384);          // 50,001 (pad to 50,016)
  int*   csrc  = (int*)(ws + 3416400);          // 600,000
  float* enorm = ws + 4016400;                  // 600,000
  float* g1    = ws + 4616400;                  // 16,384
  float4* wt   = (float4*)(ws + 4632784);       // 32,768 float4 = 131,072 w

  // zero deg+cnt (contiguous 100,000 words)
  k_zero<<<(100000 + 255) / 256, 256, 0, stream>>>(ws + 3200000, 100000);

  k_wt  <<<dim3(16, 8), 256, 0, stream>>>(W1, R1, Wc, Rc, wt);
  k_deg <<<(N_EDGES + 255) / 256, 256, 0, stream>>>(ei, deg);
  k_dinv<<<(N_NODES + 255) / 256, 256, 0, stream>>>(deg, dinv);
  k_scan<<<1, 1024, 0, stream>>>(deg, rowp);
  k_fill<<<(N_EDGES + 255) / 256, 256, 0, stream>>>(ei, rowp, cnt, dinv, csrc, enorm);

  const float* xin = x;
  for (int l = 0; l < 4; ++l) {
    const float4* Wtl = wt + (size_t)l * 4096;
    const float4* Rtl = wt + (size_t)(4 + l) * 4096;
    const float* B = (l == 0) ? b1 : bc + (size_t)(l - 1) * DIM;
    k_gemm<<<(N_NODES + 63) / 64, 1024, 0, stream>>>(xin, Wtl, Rtl, B, hwb, dlast);
    k_agg <<<(N_NODES + 7) / 8, 256, 0, stream>>>(hwb, rowp, csrc, enorm, dlast);
    xin = dlast;
  }

  k_pool2<<<N_GRAPHS, 1024, 0, stream>>>(dlast, batch, pooled);
  k_mlp1<<<N_GRAPHS, 128, 0, stream>>>(pooled, l1w, l1b, g1);
  k_mlp2<<<1, N_GRAPHS, 0, stream>>>(g1, l2w, l2b, out);
}

// Round 7
// 423.005 us; speedup vs baseline: 2.5285x; 1.5689x over previous
//
#include <hip/hip_runtime.h>

#define N_NODES  50000
#define N_EDGES  600000
#define DIM      128
#define N_GRAPHS 128
#define N_CLASSES 10
#define NB_SCAN  196          // ceil(50000/256)
#define LDSW     136          // padded LDS row width (ushort) = 128 + 8

// NOTE: harness delivers ALL integer inputs as int32 (const int*).

typedef __bf16 bf16x8 __attribute__((ext_vector_type(8)));
typedef float  f32x4  __attribute__((ext_vector_type(4)));

__device__ inline unsigned short f2bf(float f) {      // RNE float->bf16
  union { float f; unsigned int i; } u; u.f = f;
  unsigned int r = u.i + 0x7fff + ((u.i >> 16) & 1);
  return (unsigned short)(r >> 16);
}
__device__ inline float bf2f(unsigned short s) {
  union { unsigned int i; float f; } u; u.i = ((unsigned int)s) << 16;
  return u.f;
}

// ---------------- utility: zero a region ----------------

__global__ __launch_bounds__(256) void k_zero(float* __restrict__ p, int n) {
  int i = blockIdx.x * 256 + threadIdx.x;
  if (i < n) p[i] = 0.f;
}

// ---------------- weight pack: MFMA B-fragment layout, bf16 ----------------
// pk[mm*16384 + (((nt*4+kc)*64+lane)*8 + j] = bf16(M[kc*32+(lane>>4)*8+j][nt*16+(lane&15)])
// mm: 0=W1,1..3=Wc[0..2],4=R1,5..7=Rc[0..2]

__global__ __launch_bounds__(256) void k_pack(const float* __restrict__ W1,
                                              const float* __restrict__ R1,
                                              const float* __restrict__ Wc,
                                              const float* __restrict__ Rc,
                                              unsigned short* __restrict__ pk) {
  int mm = blockIdx.y;
  const float* src = (mm == 0) ? W1
                   : (mm < 4)  ? Wc + (size_t)(mm - 1) * DIM * DIM
                   : (mm == 4) ? R1
                               : Rc + (size_t)(mm - 5) * DIM * DIM;
  int idx = blockIdx.x * 256 + threadIdx.x;   // 0..2047 fragment-lane slots
  int lane = idx & 63;
  int kc   = (idx >> 6) & 3;
  int nt   = idx >> 8;
  int col  = nt * 16 + (lane & 15);
  int k0   = kc * 32 + (lane >> 4) * 8;
  unsigned short* dst = pk + (size_t)mm * 16384 + (size_t)idx * 8;
  ushort4 u;
  u.x = f2bf(src[(k0 + 0) * DIM + col]);
  u.y = f2bf(src[(k0 + 1) * DIM + col]);
  u.z = f2bf(src[(k0 + 2) * DIM + col]);
  u.w = f2bf(src[(k0 + 3) * DIM + col]);
  *(ushort4*)&dst[0] = u;
  u.x = f2bf(src[(k0 + 4) * DIM + col]);
  u.y = f2bf(src[(k0 + 5) * DIM + col]);
  u.z = f2bf(src[(k0 + 6) * DIM + col]);
  u.w = f2bf(src[(k0 + 7) * DIM + col]);
  *(ushort4*)&dst[4] = u;
}

// ---------------- CSR build ----------------

__global__ __launch_bounds__(256) void k_deg(const int* __restrict__ ei,
                                             int* __restrict__ deg) {
  int e = blockIdx.x * 256 + threadIdx.x;
  if (e < N_EDGES) atomicAdd(&deg[ei[N_EDGES + e]], 1);
}

__global__ __launch_bounds__(256) void k_dinv(const int* __restrict__ deg,
                                              float* __restrict__ dinv) {
  int n = blockIdx.x * 256 + threadIdx.x;
  if (n < N_NODES) {
    int d = deg[n];
    dinv[n] = (d > 0) ? rsqrtf((float)d) : 0.f;
  }
}

// hierarchical scan: the old single-block k_scan was the #1 dispatch (77us,
// occupancy 0.15% -- pure latency). 3 parallel kernels instead.

__global__ __launch_bounds__(256) void k_bsum(const int* __restrict__ deg,
                                              int* __restrict__ bsum) {
  int i = blockIdx.x * 256 + threadIdx.x;
  int v = (i < N_NODES) ? deg[i] : 0;
  __shared__ int tmp[256];
  int t = threadIdx.x;
  tmp[t] = v;
  __syncthreads();
  for (int off = 128; off > 0; off >>= 1) {
    if (t < off) tmp[t] += tmp[t + off];
    __syncthreads();
  }
  if (t == 0) bsum[blockIdx.x] = tmp[0];
}

__global__ __launch_bounds__(256) void k_bscan(const int* __restrict__ bsum,
                                               int* __restrict__ boff,
                                               int* __restrict__ rowp) {
  int t = threadIdx.x;
  int v = (t < NB_SCAN) ? bsum[t] : 0;
  __shared__ int tmp[256];
  tmp[t] = v;
  __syncthreads();
  for (int off = 1; off < 256; off <<= 1) {
    int add = (t >= off) ? tmp[t - off] : 0;
    __syncthreads();
    tmp[t] += add;
    __syncthreads();
  }
  boff[t] = tmp[t] - v;          // exclusive
  if (t == 0) rowp[N_NODES] = N_EDGES;
}

__global__ __launch_bounds__(256) void k_rowp(const int* __restrict__ deg,
                                              const int* __restrict__ boff,
                                              int* __restrict__ rowp) {
  int i = blockIdx.x * 256 + threadIdx.x;
  int t = threadIdx.x;
  int v = (i < N_NODES) ? deg[i] : 0;
  __shared__ int tmp[256];
  tmp[t] = v;
  __syncthreads();
  for (int off = 1; off < 256; off <<= 1) {
    int add = (t >= off) ? tmp[t - off] : 0;
    __syncthreads();
    tmp[t] += add;
    __syncthreads();
  }
  if (i < N_NODES) rowp[i] = boff[blockIdx.x] + tmp[t] - v;  // exclusive
}

__global__ __launch_bounds__(256) void k_fill(const int* __restrict__ ei,
                                              const int* __restrict__ rowp,
                                              int* __restrict__ cnt,
                                              const float* __restrict__ dinv,
                                              int* __restrict__ csrc,
                                              float* __restrict__ enorm) {
  int e = blockIdx.x * 256 + threadIdx.x;
  if (e < N_EDGES) {
    int s = ei[e];
    int d = ei[N_EDGES + e];
    int p = rowp[d] + atomicAdd(&cnt[d], 1);
    csrc[p] = s;
    enorm[p] = dinv[s] * dinv[d];
  }
}

// ---------------- MFMA dual GEMM: hwb = bf16(x@W) ; xout = x@R + b ----------------
// 256 threads (4 waves), 64-row tile, N=256 (128 W-cols ++ 128 R-cols).
// Wave w owns row-tile w (16 rows) x 16 col-tiles; 4 mfma_f32_16x16x32_bf16
// per tile (K=128). A from LDS (x staged as bf16, row pad +8 spreads banks);
// B from the pre-packed fragment buffer (same addresses for every block -> L2).
// Layouts (HW-verified): A[m=lane&15][k=(lane>>4)*8+j]; D col=lane&15,
// row=(lane>>4)*4+reg. In-place safe: rows staged to LDS before any write.

__global__ __launch_bounds__(256) void k_gemm(const float* __restrict__ xin,
                                              const unsigned short* __restrict__ pkW,
                                              const unsigned short* __restrict__ pkR,
                                              const float* __restrict__ bv,
                                              unsigned short* __restrict__ hwb,
                                              float* __restrict__ xout) {
  __shared__ unsigned short xs[64 * LDSW];
  const int tid = threadIdx.x;
  const int row0 = blockIdx.x * 64;
  // stage 64x128 fp32 -> bf16 LDS
#pragma unroll
  for (int i = 0; i < 8; ++i) {
    int idx = i * 256 + tid;            // 0..2047 float4 slots
    int r = idx >> 5, c4 = (idx & 31) * 4;
    int row = row0 + r;
    float4 v = make_float4(0.f, 0.f, 0.f, 0.f);
    if (row < N_NODES) v = *(const float4*)&xin[row * DIM + c4];
    ushort4 u;
    u.x = f2bf(v.x); u.y = f2bf(v.y); u.z = f2bf(v.z); u.w = f2bf(v.w);
    *(ushort4*)&xs[r * LDSW + c4] = u;
  }
  __syncthreads();

  const int wave = tid >> 6;            // row-tile 0..3
  const int lane = tid & 63;
  const int m = lane & 15, q = lane >> 4;

  bf16x8 a[4];
#pragma unroll
  for (int kc = 0; kc < 4; ++kc)
    a[kc] = *(const bf16x8*)&xs[(wave * 16 + m) * LDSW + kc * 32 + q * 8];

  f32x4 acc[16];
#pragma unroll
  for (int t = 0; t < 16; ++t) acc[t] = (f32x4){0.f, 0.f, 0.f, 0.f};

#pragma unroll
  for (int nt = 0; nt < 8; ++nt) {
    const unsigned short* pw = pkW + ((size_t)(nt * 4) * 64 + lane) * 8;
    const unsigned short* pr = pkR + ((size_t)(nt * 4) * 64 + lane) * 8;
#pragma unroll
    for (int kc = 0; kc < 4; ++kc) {
      bf16x8 bW = *(const bf16x8*)(pw + (size_t)kc * 64 * 8);
      acc[nt] = __builtin_amdgcn_mfma_f32_16x16x32_bf16(a[kc], bW, acc[nt], 0, 0, 0);
    }
#pragma unroll
    for (int kc = 0; kc < 4; ++kc) {
      bf16x8 bR = *(const bf16x8*)(pr + (size_t)kc * 64 * 8);
      acc[8 + nt] = __builtin_amdgcn_mfma_f32_16x16x32_bf16(a[kc], bR, acc[8 + nt], 0, 0, 0);
    }
  }

  // epilogue: W path -> hwb (bf16), R path -> xout (+bias)
#pragma unroll
  for (int nt = 0; nt < 8; ++nt) {
    int col = nt * 16 + m;
#pragma unroll
    for (int rg = 0; rg < 4; ++rg) {
      int row = row0 + wave * 16 + q * 4 + rg;
      if (row < N_NODES) hwb[row * DIM + col] = f2bf(acc[nt][rg]);
    }
  }
#pragma unroll
  for (int nt = 0; nt < 8; ++nt) {
    int col = nt * 16 + m;
    float bias = bv[col];
#pragma unroll
    for (int rg = 0; rg < 4; ++rg) {
      int row = row0 + wave * 16 + q * 4 + rg;
      if (row < N_NODES) xout[row * DIM + col] = acc[8 + nt][rg] + bias;
    }
  }
}

// ---------------- aggregation: xout[n] += sum_e norm*hw[src]; relu ----------------
// half-wave (32 lanes) per dst node; lane holds 4 dims as bf16x4 (8B gathers)

__global__ __launch_bounds__(256) void k_agg(const unsigned short* __restrict__ hwb,
                                             const int* __restrict__ rowp,
                                             const int* __restrict__ csrc,
                                             const float* __restrict__ enorm,
                                             float* __restrict__ xout) {
  int n = blockIdx.x * 8 + (threadIdx.x >> 5);
  if (n >= N_NODES) return;
  int l4 = (threadIdx.x & 31) * 4;
  float4 acc = *(const float4*)&xout[n * DIM + l4];
  int e = rowp[n], e1 = rowp[n + 1];
  for (; e + 2 <= e1; e += 2) {
    int s0 = csrc[e],  s1 = csrc[e + 1];
    float w0 = enorm[e], w1 = enorm[e + 1];
    ushort4 u0 = *(const ushort4*)&hwb[s0 * DIM + l4];
    ushort4 u1 = *(const ushort4*)&hwb[s1 * DIM + l4];
    acc.x = fmaf(w0, bf2f(u0.x), fmaf(w1, bf2f(u1.x), acc.x));
    acc.y = fmaf(w0, bf2f(u0.y), fmaf(w1, bf2f(u1.y), acc.y));
    acc.z = fmaf(w0, bf2f(u0.z), fmaf(w1, bf2f(u1.z), acc.z));
    acc.w = fmaf(w0, bf2f(u0.w), fmaf(w1, bf2f(u1.w), acc.w));
  }
  if (e < e1) {
    int s0 = csrc[e];
    float w0 = enorm[e];
    ushort4 u0 = *(const ushort4*)&hwb[s0 * DIM + l4];
    acc.x = fmaf(w0, bf2f(u0.x), acc.x);
    acc.y = fmaf(w0, bf2f(u0.y), acc.y);
    acc.z = fmaf(w0, bf2f(u0.z), acc.z);
    acc.w = fmaf(w0, bf2f(u0.w), acc.w);
  }
  acc.x = fmaxf(acc.x, 0.f);
  acc.y = fmaxf(acc.y, 0.f);
  acc.z = fmaxf(acc.z, 0.f);
  acc.w = fmaxf(acc.w, 0.f);
  *(float4*)&xout[n * DIM + l4] = acc;
}

// ---------------- global mean pool: block per graph, batch is SORTED ----------------

__global__ __launch_bounds__(1024) void k_pool2(const float* __restrict__ h,
                                                const int* __restrict__ batch,
                                                float* __restrict__ pooled) {
  int g = blockIdx.x;
  int t = threadIdx.x;
  __shared__ int sb[2];
  if (t < 2) {
    int target = g + t;                 // lower_bound(batch, target)
    int lo = 0, hi = N_NODES;
    while (lo < hi) {
      int mid = (lo + hi) >> 1;
      if (batch[mid] < target) lo = mid + 1; else hi = mid;
    }
    sb[t] = lo;
  }
  __syncthreads();
  int start = sb[0], end = sb[1];
  int c = t & 127, rg = t >> 7;         // 8 row groups
  float acc = 0.f;
  for (int r = start + rg; r < end; r += 8) acc += h[r * DIM + c];
  __shared__ float sp[8][DIM];
  sp[rg][c] = acc;
  __syncthreads();
  if (rg == 0) {
    float tot = acc;
#pragma unroll
    for (int i = 1; i < 8; ++i) tot += sp[i][c];
    float cnt = fmaxf((float)(end - start), 1.f);
    pooled[g * DIM + c] = tot / cnt;
  }
}

// ---------------- MLP head ----------------

__global__ __launch_bounds__(128) void k_mlp1(const float* __restrict__ pooled,
                                              const float* __restrict__ w,
                                              const float* __restrict__ bias,
                                              float* __restrict__ g1) {
  int g = blockIdx.x, t = threadIdx.x;
  __shared__ float sp[DIM];
  sp[t] = pooled[g * DIM + t];
  __syncthreads();
  float acc = bias[t];
#pragma unroll 4
  for (int k = 0; k < DIM; ++k) acc = fmaf(sp[k], w[k * DIM + t], acc);
  g1[g * DIM + t] = fmaxf(acc, 0.f);
}

__global__ __launch_bounds__(128) void k_mlp2(const float* __restrict__ g1,
                                              const float* __restrict__ w,
                                              const float* __restrict__ bias,
                                              float* __restrict__ out) {
  int g = threadIdx.x;   // one thread per graph
  float l[N_CLASSES];
#pragma unroll
  for (int c = 0; c < N_CLASSES; ++c) l[c] = bias[c];
  for (int k = 0; k < DIM; ++k) {
    float gv = g1[g * DIM + k];
#pragma unroll
    for (int c = 0; c < N_CLASSES; ++c) l[c] = fmaf(gv, w[k * N_CLASSES + c], l[c]);
  }
  float m = l[0];
#pragma unroll
  for (int c = 1; c < N_CLASSES; ++c) m = fmaxf(m, l[c]);
  float s = 0.f;
#pragma unroll
  for (int c = 0; c < N_CLASSES; ++c) s += expf(l[c] - m);
  float lse = logf(s) + m;
#pragma unroll
  for (int c = 0; c < N_CLASSES; ++c) out[g * N_CLASSES + c] = l[c] - lse;
}

// ---------------- launch ----------------

extern "C" void kernel_launch(void* const* d_in, const int* in_sizes, int n_in,
                              void* d_out, int out_size, void* d_ws, size_t ws_size,
                              hipStream_t stream) {
  const float* x     = (const float*)d_in[0];
  const int* ei      = (const int*)d_in[1];     // int32 on device (harness)
  const int* batch   = (const int*)d_in[2];     // int32 on device (harness)
  const float* W1  = (const float*)d_in[3];
  const float* R1  = (const float*)d_in[4];
  const float* b1  = (const float*)d_in[5];
  const float* Wc  = (const float*)d_in[6];
  const float* Rc  = (const float*)d_in[7];
  const float* bc  = (const float*)d_in[8];
  const float* l1w = (const float*)d_in[9];
  const float* l1b = (const float*)d_in[10];
  const float* l2w = (const float*)d_in[11];
  const float* l2b = (const float*)d_in[12];

  float* out   = (float*)d_out;
  float* dlast = out + N_GRAPHS * N_CLASSES;   // 'last' region; in-place layer buffer

  // ---- workspace layout (float words), ~18.8 MB ----
  float* ws    = (float*)d_ws;
  unsigned short* hwb = (unsigned short*)ws;    // 6,400,000 ushort = 3,200,000 w
  int*   deg   = (int*)(ws + 3200000);          // 50,000
  int*   cnt   = (int*)(ws + 3250000);          // 50,000
  float* pooled= ws + 3300000;                  // 16,384
  float* dinv  = ws + 3316384;                  // 50,000
  int*   rowp  = (int*)(ws + 3366384);          // 50,001 (pad to 50,016)
  int*   csrc  = (int*)(ws + 3416400);          // 600,000
  float* enorm = ws + 4016400;                  // 600,000
  float* g1    = ws + 4616400;                  // 16,384
  unsigned short* pk = (unsigned short*)(ws + 4632784); // 131,072 ushort = 65,536 w
  int*   bsum  = (int*)(ws + 4698320);          // 256
  int*   boff  = (int*)(ws + 4698576);          // 256

  // zero deg+cnt (contiguous 100,000 words)
  k_zero<<<(100000 + 255) / 256, 256, 0, stream>>>(ws + 3200000, 100000);

  k_pack<<<dim3(8, 8), 256, 0, stream>>>(W1, R1, Wc, Rc, pk);
  k_deg <<<(N_EDGES + 255) / 256, 256, 0, stream>>>(ei, deg);
  k_dinv<<<(N_NODES + 255) / 256, 256, 0, stream>>>(deg, dinv);
  k_bsum<<<NB_SCAN, 256, 0, stream>>>(deg, bsum);
  k_bscan<<<1, 256, 0, stream>>>(bsum, boff, rowp);
  k_rowp<<<NB_SCAN, 256, 0, stream>>>(deg, boff, rowp);
  k_fill<<<(N_EDGES + 255) / 256, 256, 0, stream>>>(ei, rowp, cnt, dinv, csrc, enorm);

  const float* xin = x;
  for (int l = 0; l < 4; ++l) {
    const unsigned short* pkW = pk + (size_t)l * 16384;
    const unsigned short* pkR = pk + (size_t)(4 + l) * 16384;
    const float* B = (l == 0) ? b1 : bc + (size_t)(l - 1) * DIM;
    k_gemm<<<(N_NODES + 63) / 64, 256, 0, stream>>>(xin, pkW, pkR, B, hwb, dlast);
    k_agg <<<(N_NODES + 7) / 8, 256, 0, stream>>>(hwb, rowp, csrc, enorm, dlast);
    xin = dlast;
  }

  k_pool2<<<N_GRAPHS, 1024, 0, stream>>>(dlast, batch, pooled);
  k_mlp1<<<N_GRAPHS, 128, 0, stream>>>(pooled, l1w, l1b, g1);
  k_mlp2<<<1, N_GRAPHS, 0, stream>>>(g1, l2w, l2b, out);
}

// Round 8
// 402.817 us; speedup vs baseline: 2.6552x; 1.0501x over previous
//
#include <hip/hip_runtime.h>

#define N_NODES  50000
#define N_EDGES  600000
#define DIM      128
#define N_GRAPHS 128
#define N_CLASSES 10
#define NB_SCAN  196          // ceil(50000/256)

// NOTE: harness delivers ALL integer inputs as int32 (const int*).

typedef __bf16 bf16x8 __attribute__((ext_vector_type(8)));
typedef float  f32x4  __attribute__((ext_vector_type(4)));

__device__ inline unsigned short f2bf(float f) {      // RNE float->bf16
  union { float f; unsigned int i; } u; u.f = f;
  unsigned int r = u.i + 0x7fff + ((u.i >> 16) & 1);
  return (unsigned short)(r >> 16);
}
__device__ inline float bf2f(unsigned short s) {
  union { unsigned int i; float f; } u; u.i = ((unsigned int)s) << 16;
  return u.f;
}
__device__ inline bf16x8 zero8() {
  union { bf16x8 v; unsigned long long q[2]; } u;
  u.q[0] = 0ull; u.q[1] = 0ull;
  return u.v;
}
__device__ inline bf16x8 pack8(float4 lo, float4 hi) {
  union { bf16x8 v; unsigned short s[8]; } u;
  u.s[0] = f2bf(lo.x); u.s[1] = f2bf(lo.y); u.s[2] = f2bf(lo.z); u.s[3] = f2bf(lo.w);
  u.s[4] = f2bf(hi.x); u.s[5] = f2bf(hi.y); u.s[6] = f2bf(hi.z); u.s[7] = f2bf(hi.w);
  return u.v;
}

// ---------------- utility: zero a region ----------------

__global__ __launch_bounds__(256) void k_zero(float* __restrict__ p, int n) {
  int i = blockIdx.x * 256 + threadIdx.x;
  if (i < n) p[i] = 0.f;
}

// ---------------- weight pack: MFMA B-fragment layout, bf16 ----------------
// pk[mm*16384 + ((nt*4+kc)*64+lane)*8 + j] = bf16(M[kc*32+(lane>>4)*8+j][nt*16+(lane&15)])
// mm: 0=W1,1..3=Wc[0..2],4=R1,5..7=Rc[0..2]

__global__ __launch_bounds__(256) void k_pack(const float* __restrict__ W1,
                                              const float* __restrict__ R1,
                                              const float* __restrict__ Wc,
                                              const float* __restrict__ Rc,
                                              unsigned short* __restrict__ pk) {
  int mm = blockIdx.y;
  const float* src = (mm == 0) ? W1
                   : (mm < 4)  ? Wc + (size_t)(mm - 1) * DIM * DIM
                   : (mm == 4) ? R1
                               : Rc + (size_t)(mm - 5) * DIM * DIM;
  int idx = blockIdx.x * 256 + threadIdx.x;   // 0..2047 fragment-lane slots
  int lane = idx & 63;
  int kc   = (idx >> 6) & 3;
  int nt   = idx >> 8;
  int col  = nt * 16 + (lane & 15);
  int k0   = kc * 32 + (lane >> 4) * 8;
  unsigned short* dst = pk + (size_t)mm * 16384 + (size_t)idx * 8;
  ushort4 u;
  u.x = f2bf(src[(k0 + 0) * DIM + col]);
  u.y = f2bf(src[(k0 + 1) * DIM + col]);
  u.z = f2bf(src[(k0 + 2) * DIM + col]);
  u.w = f2bf(src[(k0 + 3) * DIM + col]);
  *(ushort4*)&dst[0] = u;
  u.x = f2bf(src[(k0 + 4) * DIM + col]);
  u.y = f2bf(src[(k0 + 5) * DIM + col]);
  u.z = f2bf(src[(k0 + 6) * DIM + col]);
  u.w = f2bf(src[(k0 + 7) * DIM + col]);
  *(ushort4*)&dst[4] = u;
}

// ---------------- CSR build ----------------

__global__ __launch_bounds__(256) void k_deg(const int* __restrict__ ei,
                                             int* __restrict__ deg) {
  int e = blockIdx.x * 256 + threadIdx.x;
  if (e < N_EDGES) atomicAdd(&deg[ei[N_EDGES + e]], 1);
}

__global__ __launch_bounds__(256) void k_dinv(const int* __restrict__ deg,
                                              float* __restrict__ dinv) {
  int n = blockIdx.x * 256 + threadIdx.x;
  if (n < N_NODES) {
    int d = deg[n];
    dinv[n] = (d > 0) ? rsqrtf((float)d) : 0.f;
  }
}

__global__ __launch_bounds__(256) void k_bsum(const int* __restrict__ deg,
                                              int* __restrict__ bsum) {
  int i = blockIdx.x * 256 + threadIdx.x;
  int v = (i < N_NODES) ? deg[i] : 0;
  __shared__ int tmp[256];
  int t = threadIdx.x;
  tmp[t] = v;
  __syncthreads();
  for (int off = 128; off > 0; off >>= 1) {
    if (t < off) tmp[t] += tmp[t + off];
    __syncthreads();
  }
  if (t == 0) bsum[blockIdx.x] = tmp[0];
}

__global__ __launch_bounds__(256) void k_bscan(const int* __restrict__ bsum,
                                               int* __restrict__ boff,
                                               int* __restrict__ rowp) {
  int t = threadIdx.x;
  int v = (t < NB_SCAN) ? bsum[t] : 0;
  __shared__ int tmp[256];
  tmp[t] = v;
  __syncthreads();
  for (int off = 1; off < 256; off <<= 1) {
    int add = (t >= off) ? tmp[t - off] : 0;
    __syncthreads();
    tmp[t] += add;
    __syncthreads();
  }
  boff[t] = tmp[t] - v;          // exclusive
  if (t == 0) rowp[N_NODES] = N_EDGES;
}

__global__ __launch_bounds__(256) void k_rowp(const int* __restrict__ deg,
                                              const int* __restrict__ boff,
                                              int* __restrict__ rowp) {
  int i = blockIdx.x * 256 + threadIdx.x;
  int t = threadIdx.x;
  int v = (i < N_NODES) ? deg[i] : 0;
  __shared__ int tmp[256];
  tmp[t] = v;
  __syncthreads();
  for (int off = 1; off < 256; off <<= 1) {
    int add = (t >= off) ? tmp[t - off] : 0;
    __syncthreads();
    tmp[t] += add;
    __syncthreads();
  }
  if (i < N_NODES) rowp[i] = boff[blockIdx.x] + tmp[t] - v;  // exclusive
}

__global__ __launch_bounds__(256) void k_fill(const int* __restrict__ ei,
                                              const int* __restrict__ rowp,
                                              int* __restrict__ cnt,
                                              const float* __restrict__ dinv,
                                              int* __restrict__ csrc,
                                              float* __restrict__ enorm) {
  int e = blockIdx.x * 256 + threadIdx.x;
  if (e < N_EDGES) {
    int s = ei[e];
    int d = ei[N_EDGES + e];
    int p = rowp[d] + atomicAdd(&cnt[d], 1);
    csrc[p] = s;
    enorm[p] = dinv[s] * dinv[d];
  }
}

// ---------------- MFMA dual GEMM (LDS-free): hwb = bf16(a@W) ; skip = a@R + b ----
// 256 threads (4 waves), 64-row tile. Wave w owns rows [64b+16w, 64b+16w+16):
// A-fragments are direct global 16B loads (16 rows x 256B read exactly once,
// L1-resident); B from pre-packed fragment buffer (shared across blocks -> L2).
// No LDS, no syncthreads. In-place safe per-wave: all A reads of the wave's
// 16-row range complete before its stores to the same range.
// AF32: activation input is fp32 (layer 0 reads x). LAST: skip out is fp32.

template<bool AF32, bool LAST>
__global__ __launch_bounds__(256) void k_gemm(const void* __restrict__ act,
                                              const unsigned short* __restrict__ pkW,
                                              const unsigned short* __restrict__ pkR,
                                              const float* __restrict__ bv,
                                              unsigned short* __restrict__ hwb,
                                              unsigned short* __restrict__ skipb,
                                              float* __restrict__ skipf) {
  const int tid  = threadIdx.x;
  const int wave = tid >> 6, lane = tid & 63;
  const int m = lane & 15, q = lane >> 4;
  const int rbase = blockIdx.x * 64 + wave * 16;
  const int arow  = rbase + m;
  const bool aok  = arow < N_NODES;

  bf16x8 a[4];
  if (AF32) {
    const float* xf = (const float*)act;
#pragma unroll
    for (int kc = 0; kc < 4; ++kc) {
      float4 lo = make_float4(0.f, 0.f, 0.f, 0.f);
      float4 hi = make_float4(0.f, 0.f, 0.f, 0.f);
      if (aok) {
        lo = *(const float4*)&xf[arow * DIM + kc * 32 + q * 8];
        hi = *(const float4*)&xf[arow * DIM + kc * 32 + q * 8 + 4];
      }
      a[kc] = pack8(lo, hi);
    }
  } else {
    const unsigned short* xb = (const unsigned short*)act;
#pragma unroll
    for (int kc = 0; kc < 4; ++kc) {
      bf16x8 v = zero8();
      if (aok) v = *(const bf16x8*)&xb[arow * DIM + kc * 32 + q * 8];
      a[kc] = v;
    }
  }

  f32x4 acc[16];
#pragma unroll
  for (int t = 0; t < 16; ++t) acc[t] = (f32x4){0.f, 0.f, 0.f, 0.f};

#pragma unroll
  for (int nt = 0; nt < 8; ++nt) {
    const unsigned short* pw = pkW + ((size_t)(nt * 4) * 64 + lane) * 8;
    const unsigned short* pr = pkR + ((size_t)(nt * 4) * 64 + lane) * 8;
#pragma unroll
    for (int kc = 0; kc < 4; ++kc) {
      bf16x8 bW = *(const bf16x8*)(pw + (size_t)kc * 64 * 8);
      acc[nt] = __builtin_amdgcn_mfma_f32_16x16x32_bf16(a[kc], bW, acc[nt], 0, 0, 0);
    }
#pragma unroll
    for (int kc = 0; kc < 4; ++kc) {
      bf16x8 bR = *(const bf16x8*)(pr + (size_t)kc * 64 * 8);
      acc[8 + nt] = __builtin_amdgcn_mfma_f32_16x16x32_bf16(a[kc], bR, acc[8 + nt], 0, 0, 0);
    }
  }

  // epilogue: D col=lane&15, row=q*4+reg (within the wave's 16-row tile)
#pragma unroll
  for (int nt = 0; nt < 8; ++nt) {
    int col = nt * 16 + m;
#pragma unroll
    for (int rg = 0; rg < 4; ++rg) {
      int row = rbase + q * 4 + rg;
      if (row < N_NODES) hwb[row * DIM + col] = f2bf(acc[nt][rg]);
    }
  }
#pragma unroll
  for (int nt = 0; nt < 8; ++nt) {
    int col = nt * 16 + m;
    float bias = bv[col];
#pragma unroll
    for (int rg = 0; rg < 4; ++rg) {
      int row = rbase + q * 4 + rg;
      if (row < N_NODES) {
        float v = acc[8 + nt][rg] + bias;
        if (LAST) skipf[row * DIM + col] = v;
        else      skipb[row * DIM + col] = f2bf(v);
      }
    }
  }
}

// ---------------- aggregation: act[n] = relu(skip[n] + sum_e norm*hw[src]) ----------
// half-wave (32 lanes) per dst node; lane holds 4 dims (bf16x4, 8B gathers);
// 4-edge unroll for memory-level parallelism. LAST: skip/out are fp32 (dlast).

template<bool LAST>
__global__ __launch_bounds__(256) void k_agg(const unsigned short* __restrict__ hwb,
                                             const int* __restrict__ rowp,
                                             const int* __restrict__ csrc,
                                             const float* __restrict__ enorm,
                                             unsigned short* __restrict__ actb,
                                             float* __restrict__ actf) {
  int n = blockIdx.x * 8 + (threadIdx.x >> 5);
  if (n >= N_NODES) return;
  int l4 = (threadIdx.x & 31) * 4;
  float4 acc;
  if (LAST) {
    acc = *(const float4*)&actf[n * DIM + l4];
  } else {
    ushort4 s = *(const ushort4*)&actb[n * DIM + l4];
    acc = make_float4(bf2f(s.x), bf2f(s.y), bf2f(s.z), bf2f(s.w));
  }
  int e = rowp[n], e1 = rowp[n + 1];
  for (; e + 4 <= e1; e += 4) {
    int s0 = csrc[e],     s1 = csrc[e + 1], s2 = csrc[e + 2], s3 = csrc[e + 3];
    float w0 = enorm[e],  w1 = enorm[e + 1], w2 = enorm[e + 2], w3 = enorm[e + 3];
    ushort4 u0 = *(const ushort4*)&hwb[s0 * DIM + l4];
    ushort4 u1 = *(const ushort4*)&hwb[s1 * DIM + l4];
    ushort4 u2 = *(const ushort4*)&hwb[s2 * DIM + l4];
    ushort4 u3 = *(const ushort4*)&hwb[s3 * DIM + l4];
    acc.x = fmaf(w0, bf2f(u0.x), fmaf(w1, bf2f(u1.x), fmaf(w2, bf2f(u2.x), fmaf(w3, bf2f(u3.x), acc.x))));
    acc.y = fmaf(w0, bf2f(u0.y), fmaf(w1, bf2f(u1.y), fmaf(w2, bf2f(u2.y), fmaf(w3, bf2f(u3.y), acc.y))));
    acc.z = fmaf(w0, bf2f(u0.z), fmaf(w1, bf2f(u1.z), fmaf(w2, bf2f(u2.z), fmaf(w3, bf2f(u3.z), acc.z))));
    acc.w = fmaf(w0, bf2f(u0.w), fmaf(w1, bf2f(u1.w), fmaf(w2, bf2f(u2.w), fmaf(w3, bf2f(u3.w), acc.w))));
  }
  for (; e < e1; ++e) {
    int s0 = csrc[e];
    float w0 = enorm[e];
    ushort4 u0 = *(const ushort4*)&hwb[s0 * DIM + l4];
    acc.x = fmaf(w0, bf2f(u0.x), acc.x);
    acc.y = fmaf(w0, bf2f(u0.y), acc.y);
    acc.z = fmaf(w0, bf2f(u0.z), acc.z);
    acc.w = fmaf(w0, bf2f(u0.w), acc.w);
  }
  acc.x = fmaxf(acc.x, 0.f);
  acc.y = fmaxf(acc.y, 0.f);
  acc.z = fmaxf(acc.z, 0.f);
  acc.w = fmaxf(acc.w, 0.f);
  if (LAST) {
    *(float4*)&actf[n * DIM + l4] = acc;
  } else {
    ushort4 o;
    o.x = f2bf(acc.x); o.y = f2bf(acc.y); o.z = f2bf(acc.z); o.w = f2bf(acc.w);
    *(ushort4*)&actb[n * DIM + l4] = o;
  }
}

// ---------------- global mean pool: block per graph, batch is SORTED ----------------

__global__ __launch_bounds__(1024) void k_pool2(const float* __restrict__ h,
                                                const int* __restrict__ batch,
                                                float* __restrict__ pooled) {
  int g = blockIdx.x;
  int t = threadIdx.x;
  __shared__ int sb[2];
  if (t < 2) {
    int target = g + t;                 // lower_bound(batch, target)
    int lo = 0, hi = N_NODES;
    while (lo < hi) {
      int mid = (lo + hi) >> 1;
      if (batch[mid] < target) lo = mid + 1; else hi = mid;
    }
    sb[t] = lo;
  }
  __syncthreads();
  int start = sb[0], end = sb[1];
  int c = t & 127, rg = t >> 7;         // 8 row groups
  float acc = 0.f;
  for (int r = start + rg; r < end; r += 8) acc += h[r * DIM + c];
  __shared__ float sp[8][DIM];
  sp[rg][c] = acc;
  __syncthreads();
  if (rg == 0) {
    float tot = acc;
#pragma unroll
    for (int i = 1; i < 8; ++i) tot += sp[i][c];
    float cnt = fmaxf((float)(end - start), 1.f);
    pooled[g * DIM + c] = tot / cnt;
  }
}

// ---------------- MLP head ----------------

__global__ __launch_bounds__(128) void k_mlp1(const float* __restrict__ pooled,
                                              const float* __restrict__ w,
                                              const float* __restrict__ bias,
                                              float* __restrict__ g1) {
  int g = blockIdx.x, t = threadIdx.x;
  __shared__ float sp[DIM];
  sp[t] = pooled[g * DIM + t];
  __syncthreads();
  float acc = bias[t];
#pragma unroll 4
  for (int k = 0; k < DIM; ++k) acc = fmaf(sp[k], w[k * DIM + t], acc);
  g1[g * DIM + t] = fmaxf(acc, 0.f);
}

__global__ __launch_bounds__(128) void k_mlp2(const float* __restrict__ g1,
                                              const float* __restrict__ w,
                                              const float* __restrict__ bias,
                                              float* __restrict__ out) {
  int g = threadIdx.x;   // one thread per graph
  float l[N_CLASSES];
#pragma unroll
  for (int c = 0; c < N_CLASSES; ++c) l[c] = bias[c];
  for (int k = 0; k < DIM; ++k) {
    float gv = g1[g * DIM + k];
#pragma unroll
    for (int c = 0; c < N_CLASSES; ++c) l[c] = fmaf(gv, w[k * N_CLASSES + c], l[c]);
  }
  float m = l[0];
#pragma unroll
  for (int c = 1; c < N_CLASSES; ++c) m = fmaxf(m, l[c]);
  float s = 0.f;
#pragma unroll
  for (int c = 0; c < N_CLASSES; ++c) s += expf(l[c] - m);
  float lse = logf(s) + m;
#pragma unroll
  for (int c = 0; c < N_CLASSES; ++c) out[g * N_CLASSES + c] = l[c] - lse;
}

// ---------------- launch ----------------

extern "C" void kernel_launch(void* const* d_in, const int* in_sizes, int n_in,
                              void* d_out, int out_size, void* d_ws, size_t ws_size,
                              hipStream_t stream) {
  const float* x     = (const float*)d_in[0];
  const int* ei      = (const int*)d_in[1];     // int32 on device (harness)
  const int* batch   = (const int*)d_in[2];     // int32 on device (harness)
  const float* W1  = (const float*)d_in[3];
  const float* R1  = (const float*)d_in[4];
  const float* b1  = (const float*)d_in[5];
  const float* Wc  = (const float*)d_in[6];
  const float* Rc  = (const float*)d_in[7];
  const float* bc  = (const float*)d_in[8];
  const float* l1w = (const float*)d_in[9];
  const float* l1b = (const float*)d_in[10];
  const float* l2w = (const float*)d_in[11];
  const float* l2b = (const float*)d_in[12];

  float* out   = (float*)d_out;
  float* dlast = out + N_GRAPHS * N_CLASSES;   // 'last' region (fp32 layer-4 buffer)

  // ---- workspace layout (float words), ~31 MB ----
  float* ws    = (float*)d_ws;
  unsigned short* hwb  = (unsigned short*)ws;              // 6.4M ushort = 3.2M w
  unsigned short* actb = (unsigned short*)(ws + 3200000);  // 6.4M ushort = 3.2M w
  int*   deg   = (int*)(ws + 6400000);          // 50,000
  int*   cnt   = (int*)(ws + 6450000);          // 50,000
  float* pooled= ws + 6500000;                  // 16,384
  float* dinv  = ws + 6516384;                  // 50,000
  int*   rowp  = (int*)(ws + 6566384);          // 50,001 (pad to 50,016)
  int*   csrc  = (int*)(ws + 6616400);          // 600,000
  float* enorm = ws + 7216400;                  // 600,000
  float* g1    = ws + 7816400;                  // 16,384
  unsigned short* pk = (unsigned short*)(ws + 7832784); // 131,072 ushort = 65,536 w
  int*   bsum  = (int*)(ws + 7898320);          // 256
  int*   boff  = (int*)(ws + 7898576);          // 256

  // zero deg+cnt (contiguous 100,000 words)
  k_zero<<<(100000 + 255) / 256, 256, 0, stream>>>(ws + 6400000, 100000);

  k_pack<<<dim3(8, 8), 256, 0, stream>>>(W1, R1, Wc, Rc, pk);
  k_deg <<<(N_EDGES + 255) / 256, 256, 0, stream>>>(ei, deg);
  k_dinv<<<(N_NODES + 255) / 256, 256, 0, stream>>>(deg, dinv);
  k_bsum<<<NB_SCAN, 256, 0, stream>>>(deg, bsum);
  k_bscan<<<1, 256, 0, stream>>>(bsum, boff, rowp);
  k_rowp<<<NB_SCAN, 256, 0, stream>>>(deg, boff, rowp);
  k_fill<<<(N_EDGES + 255) / 256, 256, 0, stream>>>(ei, rowp, cnt, dinv, csrc, enorm);

  const int NGB = (N_NODES + 63) / 64;    // 782
  const int NAB = (N_NODES + 7) / 8;      // 6250

  // layer 0: x (fp32) -> actb (bf16)
  k_gemm<true, false><<<NGB, 256, 0, stream>>>(
      x, pk + 0 * 16384, pk + 4 * 16384, b1, hwb, actb, nullptr);
  k_agg<false><<<NAB, 256, 0, stream>>>(hwb, rowp, csrc, enorm, actb, nullptr);

  // layers 1,2: actb -> actb (bf16, in-place per-wave safe)
  for (int l = 1; l <= 2; ++l) {
    k_gemm<false, false><<<NGB, 256, 0, stream>>>(
        actb, pk + (size_t)l * 16384, pk + (size_t)(4 + l) * 16384,
        bc + (size_t)(l - 1) * DIM, hwb, actb, nullptr);
    k_agg<false><<<NAB, 256, 0, stream>>>(hwb, rowp, csrc, enorm, actb, nullptr);
  }

  // layer 3: actb -> dlast (fp32)
  k_gemm<false, true><<<NGB, 256, 0, stream>>>(
      actb, pk + 3 * 16384, pk + 7 * 16384, bc + 2 * DIM, hwb, nullptr, dlast);
  k_agg<true><<<NAB, 256, 0, stream>>>(hwb, rowp, csrc, enorm, nullptr, dlast);

  k_pool2<<<N_GRAPHS, 1024, 0, stream>>>(dlast, batch, pooled);
  k_mlp1<<<N_GRAPHS, 128, 0, stream>>>(pooled, l1w, l1b, g1);
  k_mlp2<<<1, N_GRAPHS, 0, stream>>>(g1, l2w, l2b, out);
}

// Round 10
// 394.402 us; speedup vs baseline: 2.7118x; 1.0213x over previous
//
#include <hip/hip_runtime.h>

#define N_NODES  50000
#define N_EDGES  600000
#define DIM      128
#define N_GRAPHS 128
#define N_CLASSES 10
#define NB_SCAN  196          // ceil(50000/256)
#define LDSW     136          // padded LDS row width in ushorts
#define NZB      6266         // zero blocks: ceil(1604000/256)

// NOTE: harness delivers ALL integer inputs as int32 (const int*).

typedef __bf16 bf16x8 __attribute__((ext_vector_type(8)));
typedef float  f32x4  __attribute__((ext_vector_type(4)));

__device__ inline unsigned short f2bf(float f) {      // RNE float->bf16
  union { float f; unsigned int i; } u; u.f = f;
  unsigned int r = u.i + 0x7fff + ((u.i >> 16) & 1);
  return (unsigned short)(r >> 16);
}
__device__ inline float bf2f(unsigned short s) {
  union { unsigned int i; float f; } u; u.i = ((unsigned int)s) << 16;
  return u.f;
}
__device__ inline bf16x8 pack8(float4 lo, float4 hi) {
  union { bf16x8 v; unsigned short s[8]; } u;
  u.s[0] = f2bf(lo.x); u.s[1] = f2bf(lo.y); u.s[2] = f2bf(lo.z); u.s[3] = f2bf(lo.w);
  u.s[4] = f2bf(hi.x); u.s[5] = f2bf(hi.y); u.s[6] = f2bf(hi.z); u.s[7] = f2bf(hi.w);
  return u.v;
}

// ---------------- prep: zero CSR scratch + pack weights (fused) ----------------
// blocks [0,NZB): zero deg+cnt+csrc+enorm (1,604,000 words, contiguous).
// blocks [NZB, NZB+64): pack 8 matrices into MFMA B-fragment layout, bf16.
// pk[mm*16384 + ((nt*4+kc)*64+lane)*8 + j] =
//     bf16(M[kc*32+(lane>>4)*8+j][nt*16+(lane&15)])

__global__ __launch_bounds__(256) void k_prep(float* __restrict__ zbase,
                                              const float* __restrict__ W1,
                                              const float* __restrict__ R1,
                                              const float* __restrict__ Wc,
                                              const float* __restrict__ Rc,
                                              unsigned short* __restrict__ pk) {
  if (blockIdx.x < NZB) {
    int i = blockIdx.x * 256 + threadIdx.x;
    if (i < 1604000) zbase[i] = 0.f;
    return;
  }
  int pb = blockIdx.x - NZB;            // 0..63
  int mm = pb >> 3, sub = pb & 7;
  const float* src = (mm == 0) ? W1
                   : (mm < 4)  ? Wc + (size_t)(mm - 1) * DIM * DIM
                   : (mm == 4) ? R1
                               : Rc + (size_t)(mm - 5) * DIM * DIM;
  int idx = sub * 256 + threadIdx.x;    // 0..2047 fragment-lane slots
  int lane = idx & 63;
  int kc   = (idx >> 6) & 3;
  int nt   = idx >> 8;
  int col  = nt * 16 + (lane & 15);
  int k0   = kc * 32 + (lane >> 4) * 8;
  unsigned short* dst = pk + (size_t)mm * 16384 + (size_t)idx * 8;
  ushort4 u;
  u.x = f2bf(src[(k0 + 0) * DIM + col]);
  u.y = f2bf(src[(k0 + 1) * DIM + col]);
  u.z = f2bf(src[(k0 + 2) * DIM + col]);
  u.w = f2bf(src[(k0 + 3) * DIM + col]);
  *(ushort4*)&dst[0] = u;
  u.x = f2bf(src[(k0 + 4) * DIM + col]);
  u.y = f2bf(src[(k0 + 5) * DIM + col]);
  u.z = f2bf(src[(k0 + 6) * DIM + col]);
  u.w = f2bf(src[(k0 + 7) * DIM + col]);
  *(ushort4*)&dst[4] = u;
}

// ---------------- CSR build (padded: per-node degree rounded up to x4) --------

__global__ __launch_bounds__(256) void k_deg(const int* __restrict__ ei,
                                             int* __restrict__ deg) {
  int e = blockIdx.x * 256 + threadIdx.x;
  if (e < N_EDGES) atomicAdd(&deg[ei[N_EDGES + e]], 1);
}

// dinv + per-block padded-degree sum (fused)
__global__ __launch_bounds__(256) void k_dinvsum(const int* __restrict__ deg,
                                                 float* __restrict__ dinv,
                                                 int* __restrict__ bsum) {
  int i = blockIdx.x * 256 + threadIdx.x;
  int t = threadIdx.x;
  int d = (i < N_NODES) ? deg[i] : 0;
  if (i < N_NODES) dinv[i] = (d > 0) ? rsqrtf((float)d) : 0.f;
  int dp = (d + 3) & ~3;
  __shared__ int tmp[256];
  tmp[t] = dp;
  __syncthreads();
  for (int off = 128; off > 0; off >>= 1) {
    if (t < off) tmp[t] += tmp[t + off];
    __syncthreads();
  }
  if (t == 0) bsum[blockIdx.x] = tmp[0];
}

__global__ __launch_bounds__(256) void k_bscan(const int* __restrict__ bsum,
                                               int* __restrict__ boff,
                                               int* __restrict__ rowp) {
  int t = threadIdx.x;
  int v = (t < NB_SCAN) ? bsum[t] : 0;
  __shared__ int tmp[256];
  tmp[t] = v;
  __syncthreads();
  for (int off = 1; off < 256; off <<= 1) {
    int add = (t >= off) ? tmp[t - off] : 0;
    __syncthreads();
    tmp[t] += add;
    __syncthreads();
  }
  boff[t] = tmp[t] - v;          // exclusive
  if (t == 255) rowp[N_NODES] = tmp[255];   // total padded edge count
}

__global__ __launch_bounds__(256) void k_rowp(const int* __restrict__ deg,
                                              const int* __restrict__ boff,
                                              int* __restrict__ rowp) {
  int i = blockIdx.x * 256 + threadIdx.x;
  int t = threadIdx.x;
  int dp = (i < N_NODES) ? ((deg[i] + 3) & ~3) : 0;
  __shared__ int tmp[256];
  tmp[t] = dp;
  __syncthreads();
  for (int off = 1; off < 256; off <<= 1) {
    int add = (t >= off) ? tmp[t - off] : 0;
    __syncthreads();
    tmp[t] += add;
    __syncthreads();
  }
  if (i < N_NODES) rowp[i] = boff[blockIdx.x] + tmp[t] - dp;  // exclusive
}

__global__ __launch_bounds__(256) void k_fill(const int* __restrict__ ei,
                                              const int* __restrict__ rowp,
                                              int* __restrict__ cnt,
                                              const float* __restrict__ dinv,
                                              int* __restrict__ csrc,
                                              float* __restrict__ enorm) {
  int e = blockIdx.x * 256 + threadIdx.x;
  if (e < N_EDGES) {
    int s = ei[e];
    int d = ei[N_EDGES + e];
    int p = rowp[d] + atomicAdd(&cnt[d], 1);
    csrc[p] = s;
    enorm[p] = dinv[s] * dinv[d];
    // padding slots [rowp[d]+deg, rowp[d]+degpad) stay zeroed by k_prep:
    // src=0 (valid row), w=0 -> contributes nothing.
  }
}

// ---------------- layer-0 MFMA dual GEMM: h0 = bf16(x@W1) ; skipb = x@R1+b1 ---
// 256 threads (4 waves), 64-row tile; A direct from global fp32 x (16B loads);
// B from packed fragments (block-shared addresses -> L2).
// Layouts (HW-verified): A[m=lane&15][k=(lane>>4)*8+j]; D col=lane&15,
// row=(lane>>4)*4+reg.

__global__ __launch_bounds__(256) void k_gemm0(const float* __restrict__ xf,
                                               const unsigned short* __restrict__ pkW,
                                               const unsigned short* __restrict__ pkR,
                                               const float* __restrict__ bv,
                                               unsigned short* __restrict__ hwb,
                                               unsigned short* __restrict__ skipb) {
  const int tid  = threadIdx.x;
  const int wave = tid >> 6, lane = tid & 63;
  const int m = lane & 15, q = lane >> 4;
  const int rbase = blockIdx.x * 64 + wave * 16;
  const int arow  = rbase + m;
  const bool aok  = arow < N_NODES;

  bf16x8 a[4];
#pragma unroll
  for (int kc = 0; kc < 4; ++kc) {
    float4 lo = make_float4(0.f, 0.f, 0.f, 0.f);
    float4 hi = make_float4(0.f, 0.f, 0.f, 0.f);
    if (aok) {
      lo = *(const float4*)&xf[arow * DIM + kc * 32 + q * 8];
      hi = *(const float4*)&xf[arow * DIM + kc * 32 + q * 8 + 4];
    }
    a[kc] = pack8(lo, hi);
  }

  f32x4 acc[16];
#pragma unroll
  for (int t = 0; t < 16; ++t) acc[t] = (f32x4){0.f, 0.f, 0.f, 0.f};

#pragma unroll
  for (int nt = 0; nt < 8; ++nt) {
    const unsigned short* pw = pkW + ((size_t)(nt * 4) * 64 + lane) * 8;
    const unsigned short* pr = pkR + ((size_t)(nt * 4) * 64 + lane) * 8;
#pragma unroll
    for (int kc = 0; kc < 4; ++kc) {
      bf16x8 bW = *(const bf16x8*)(pw + (size_t)kc * 64 * 8);
      acc[nt] = __builtin_amdgcn_mfma_f32_16x16x32_bf16(a[kc], bW, acc[nt], 0, 0, 0);
    }
#pragma unroll
    for (int kc = 0; kc < 4; ++kc) {
      bf16x8 bR = *(const bf16x8*)(pr + (size_t)kc * 64 * 8);
      acc[8 + nt] = __builtin_amdgcn_mfma_f32_16x16x32_bf16(a[kc], bR, acc[8 + nt], 0, 0, 0);
    }
  }

#pragma unroll
  for (int nt = 0; nt < 8; ++nt) {
    int col = nt * 16 + m;
    float bias = bv[col];
#pragma unroll
    for (int rg = 0; rg < 4; ++rg) {
      int row = rbase + q * 4 + rg;
      if (row < N_NODES) {
        hwb[row * DIM + col]   = f2bf(acc[nt][rg]);
        skipb[row * DIM + col] = f2bf(acc[8 + nt][rg] + bias);
      }
    }
  }
}

// ---------------- fused agg(l) + gemm(l+1) ------------------------------------
// Block owns rows [64b, 64b+64).
// Phase A: act = relu(skipb + sum_e norm*hin[src]) for own rows -> LDS (bf16).
//   half-wave per node, 4-dim lanes; padded CSR -> branch-free 4-wide edge loop
//   with int4/float4 metadata loads.
// Phase B: gemm on LDS act: hout = bf16(act@W); skip' = act@R + b
//   (in-place skipb for mid layers; fp32 skipf for the last layer).
// hin/hout MUST be distinct buffers (cross-block gather); skipb in-place is
// safe (each block touches only its own rows, syncthreads between phases).

template<bool LAST>
__global__ __launch_bounds__(256) void k_aggemm(const unsigned short* __restrict__ hin,
                                                const int* __restrict__ rowp,
                                                const int* __restrict__ csrc,
                                                const float* __restrict__ enorm,
                                                const unsigned short* __restrict__ pkW,
                                                const unsigned short* __restrict__ pkR,
                                                const float* __restrict__ bv,
                                                unsigned short* __restrict__ hout,
                                                unsigned short* __restrict__ skipb,
                                                float* __restrict__ skipf) {
  __shared__ unsigned short xs[64 * LDSW];
  const int tid = threadIdx.x;
  const int row0 = blockIdx.x * 64;

  // ---- phase A ----
  {
    int hw = tid >> 5;
    int l4 = (tid & 31) * 4;
    for (int rnd = 0; rnd < 8; ++rnd) {
      int n = row0 + rnd * 8 + hw;
      float4 acc = make_float4(0.f, 0.f, 0.f, 0.f);
      if (n < N_NODES) {
        ushort4 s = *(const ushort4*)&skipb[n * DIM + l4];
        acc = make_float4(bf2f(s.x), bf2f(s.y), bf2f(s.z), bf2f(s.w));
        int e0 = rowp[n], e1 = rowp[n + 1];
        for (int e = e0; e < e1; e += 4) {
          int4   cs = *(const int4*)&csrc[e];
          float4 wv = *(const float4*)&enorm[e];
          ushort4 u0 = *(const ushort4*)&hin[cs.x * DIM + l4];
          ushort4 u1 = *(const ushort4*)&hin[cs.y * DIM + l4];
          ushort4 u2 = *(const ushort4*)&hin[cs.z * DIM + l4];
          ushort4 u3 = *(const ushort4*)&hin[cs.w * DIM + l4];
          acc.x = fmaf(wv.x, bf2f(u0.x), fmaf(wv.y, bf2f(u1.x), fmaf(wv.z, bf2f(u2.x), fmaf(wv.w, bf2f(u3.x), acc.x))));
          acc.y = fmaf(wv.x, bf2f(u0.y), fmaf(wv.y, bf2f(u1.y), fmaf(wv.z, bf2f(u2.y), fmaf(wv.w, bf2f(u3.y), acc.y))));
          acc.z = fmaf(wv.x, bf2f(u0.z), fmaf(wv.y, bf2f(u1.z), fmaf(wv.z, bf2f(u2.z), fmaf(wv.w, bf2f(u3.z), acc.z))));
          acc.w = fmaf(wv.x, bf2f(u0.w), fmaf(wv.y, bf2f(u1.w), fmaf(wv.z, bf2f(u2.w), fmaf(wv.w, bf2f(u3.w), acc.w))));
        }
        acc.x = fmaxf(acc.x, 0.f);
        acc.y = fmaxf(acc.y, 0.f);
        acc.z = fmaxf(acc.z, 0.f);
        acc.w = fmaxf(acc.w, 0.f);
      }
      int r = rnd * 8 + hw;
      ushort4 o;
      o.x = f2bf(acc.x); o.y = f2bf(acc.y); o.z = f2bf(acc.z); o.w = f2bf(acc.w);
      *(ushort4*)&xs[r * LDSW + l4] = o;
    }
  }
  __syncthreads();

  // ---- phase B ----
  const int wave = tid >> 6, lane = tid & 63;
  const int m = lane & 15, q = lane >> 4;
  const int rbase = row0 + wave * 16;

  bf16x8 a[4];
#pragma unroll
  for (int kc = 0; kc < 4; ++kc)
    a[kc] = *(const bf16x8*)&xs[(wave * 16 + m) * LDSW + kc * 32 + q * 8];

  f32x4 acc[16];
#pragma unroll
  for (int t = 0; t < 16; ++t) acc[t] = (f32x4){0.f, 0.f, 0.f, 0.f};

#pragma unroll
  for (int nt = 0; nt < 8; ++nt) {
    const unsigned short* pw = pkW + ((size_t)(nt * 4) * 64 + lane) * 8;
    const unsigned short* pr = pkR + ((size_t)(nt * 4) * 64 + lane) * 8;
#pragma unroll
    for (int kc = 0; kc < 4; ++kc) {
      bf16x8 bW = *(const bf16x8*)(pw + (size_t)kc * 64 * 8);
      acc[nt] = __builtin_amdgcn_mfma_f32_16x16x32_bf16(a[kc], bW, acc[nt], 0, 0, 0);
    }
#pragma unroll
    for (int kc = 0; kc < 4; ++kc) {
      bf16x8 bR = *(const bf16x8*)(pr + (size_t)kc * 64 * 8);
      acc[8 + nt] = __builtin_amdgcn_mfma_f32_16x16x32_bf16(a[kc], bR, acc[8 + nt], 0, 0, 0);
    }
  }

#pragma unroll
  for (int nt = 0; nt < 8; ++nt) {
    int col = nt * 16 + m;
    float bias = bv[col];
#pragma unroll
    for (int rg = 0; rg < 4; ++rg) {
      int row = rbase + q * 4 + rg;
      if (row < N_NODES) {
        hout[row * DIM + col] = f2bf(acc[nt][rg]);
        float v = acc[8 + nt][rg] + bias;
        if (LAST) skipf[row * DIM + col] = v;
        else      skipb[row * DIM + col] = f2bf(v);
      }
    }
  }
}

// ---------------- final aggregation: dlast = relu(dlast + gather(hwb)) --------

__global__ __launch_bounds__(256) void k_aggF(const unsigned short* __restrict__ hwb,
                                              const int* __restrict__ rowp,
                                              const int* __restrict__ csrc,
                                              const float* __restrict__ enorm,
                                              float* __restrict__ actf) {
  int n = blockIdx.x * 8 + (threadIdx.x >> 5);
  if (n >= N_NODES) return;
  int l4 = (threadIdx.x & 31) * 4;
  float4 acc = *(const float4*)&actf[n * DIM + l4];
  int e0 = rowp[n], e1 = rowp[n + 1];
  for (int e = e0; e < e1; e += 4) {
    int4   cs = *(const int4*)&csrc[e];
    float4 wv = *(const float4*)&enorm[e];
    ushort4 u0 = *(const ushort4*)&hwb[cs.x * DIM + l4];
    ushort4 u1 = *(const ushort4*)&hwb[cs.y * DIM + l4];
    ushort4 u2 = *(const ushort4*)&hwb[cs.z * DIM + l4];
    ushort4 u3 = *(const ushort4*)&hwb[cs.w * DIM + l4];
    acc.x = fmaf(wv.x, bf2f(u0.x), fmaf(wv.y, bf2f(u1.x), fmaf(wv.z, bf2f(u2.x), fmaf(wv.w, bf2f(u3.x), acc.x))));
    acc.y = fmaf(wv.x, bf2f(u0.y), fmaf(wv.y, bf2f(u1.y), fmaf(wv.z, bf2f(u2.y), fmaf(wv.w, bf2f(u3.y), acc.y))));
    acc.z = fmaf(wv.x, bf2f(u0.z), fmaf(wv.y, bf2f(u1.z), fmaf(wv.z, bf2f(u2.z), fmaf(wv.w, bf2f(u3.z), acc.z))));
    acc.w = fmaf(wv.x, bf2f(u0.w), fmaf(wv.y, bf2f(u1.w), fmaf(wv.z, bf2f(u2.w), fmaf(wv.w, bf2f(u3.w), acc.w))));
  }
  acc.x = fmaxf(acc.x, 0.f);
  acc.y = fmaxf(acc.y, 0.f);
  acc.z = fmaxf(acc.z, 0.f);
  acc.w = fmaxf(acc.w, 0.f);
  *(float4*)&actf[n * DIM + l4] = acc;
}

// ---------------- global mean pool: block per graph, batch is SORTED ----------

__global__ __launch_bounds__(1024) void k_pool2(const float* __restrict__ h,
                                                const int* __restrict__ batch,
                                                float* __restrict__ pooled) {
  int g = blockIdx.x;
  int t = threadIdx.x;
  __shared__ int sb[2];
  if (t < 2) {
    int target = g + t;                 // lower_bound(batch, target)
    int lo = 0, hi = N_NODES;
    while (lo < hi) {
      int mid = (lo + hi) >> 1;
      if (batch[mid] < target) lo = mid + 1; else hi = mid;
    }
    sb[t] = lo;
  }
  __syncthreads();
  int start = sb[0], end = sb[1];
  int c = t & 127, rg = t >> 7;         // 8 row groups
  float acc = 0.f;
  for (int r = start + rg; r < end; r += 8) acc += h[r * DIM + c];
  __shared__ float sp[8][DIM];
  sp[rg][c] = acc;
  __syncthreads();
  if (rg == 0) {
    float tot = acc;
#pragma unroll
    for (int i = 1; i < 8; ++i) tot += sp[i][c];
    float cnt = fmaxf((float)(end - start), 1.f);
    pooled[g * DIM + c] = tot / cnt;
  }
}

// ---------------- MLP head ----------------

__global__ __launch_bounds__(128) void k_mlp1(const float* __restrict__ pooled,
                                              const float* __restrict__ w,
                                              const float* __restrict__ bias,
                                              float* __restrict__ g1) {
  int g = blockIdx.x, t = threadIdx.x;
  __shared__ float sp[DIM];
  sp[t] = pooled[g * DIM + t];
  __syncthreads();
  float acc = bias[t];
#pragma unroll 4
  for (int k = 0; k < DIM; ++k) acc = fmaf(sp[k], w[k * DIM + t], acc);
  g1[g * DIM + t] = fmaxf(acc, 0.f);
}

__global__ __launch_bounds__(128) void k_mlp2(const float* __restrict__ g1,
                                              const float* __restrict__ w,
                                              const float* __restrict__ bias,
                                              float* __restrict__ out) {
  int g = threadIdx.x;   // one thread per graph
  float l[N_CLASSES];
#pragma unroll
  for (int c = 0; c < N_CLASSES; ++c) l[c] = bias[c];
  for (int k = 0; k < DIM; ++k) {
    float gv = g1[g * DIM + k];
#pragma unroll
    for (int c = 0; c < N_CLASSES; ++c) l[c] = fmaf(gv, w[k * N_CLASSES + c], l[c]);
  }
  float m = l[0];
#pragma unroll
  for (int c = 1; c < N_CLASSES; ++c) m = fmaxf(m, l[c]);
  float s = 0.f;
#pragma unroll
  for (int c = 0; c < N_CLASSES; ++c) s += expf(l[c] - m);
  float lse = logf(s) + m;
#pragma unroll
  for (int c = 0; c < N_CLASSES; ++c) out[g * N_CLASSES + c] = l[c] - lse;
}

// ---------------- launch ----------------

extern "C" void kernel_launch(void* const* d_in, const int* in_sizes, int n_in,
                              void* d_out, int out_size, void* d_ws, size_t ws_size,
                              hipStream_t stream) {
  const float* x     = (const float*)d_in[0];
  const int* ei      = (const int*)d_in[1];     // int32 on device (harness)
  const int* batch   = (const int*)d_in[2];     // int32 on device (harness)
  const float* W1  = (const float*)d_in[3];
  const float* R1  = (const float*)d_in[4];
  const float* b1  = (const float*)d_in[5];
  const float* Wc  = (const float*)d_in[6];
  const float* Rc  = (const float*)d_in[7];
  const float* bc  = (const float*)d_in[8];
  const float* l1w = (const float*)d_in[9];
  const float* l1b = (const float*)d_in[10];
  const float* l2w = (const float*)d_in[11];
  const float* l2b = (const float*)d_in[12];

  float* out   = (float*)d_out;
  float* dlast = out + N_GRAPHS * N_CLASSES;   // 'last' region (fp32 layer-4 buffer)

  // workspace layout (float-word offsets), ~45.6 MB total:
  //   0         h0    (3.2M w, bf16 x 6.4M)
  //   3200000   h1    (3.2M w)
  //   6400000   skipb (3.2M w)
  //   9600000   deg   (50,000)      -- zero region start
  //   9650000   cnt   (50,000)
  //   9700000   csrc  (752,000)
  //   10452000  enorm (752,000)     -- zero region end (1,604,000 words)
  //   11204000  dinv  (50,000)
  //   11254000  rowp  (50,016)
  //   11304016  pooled(16,384)
  //   11320400  g1    (16,384)
  //   11336784  pk    (65,536 w = 131,072 ushort)
  //   11402320  bsum  (256)
  //   11402576  boff  (256)
  float* ws = (float*)d_ws;
  unsigned short* h0    = (unsigned short*)ws;
  unsigned short* h1    = (unsigned short*)(ws + 3200000);
  unsigned short* skipb = (unsigned short*)(ws + 6400000);
  int*   deg   = (int*)(ws + 9600000);
  int*   cnt   = (int*)(ws + 9650000);
  int*   csrc  = (int*)(ws + 9700000);
  float* enorm = ws + 10452000;
  float* dinv  = ws + 11204000;
  int*   rowp  = (int*)(ws + 11254000);
  float* pooled= ws + 11304016;
  float* g1    = ws + 11320400;
  unsigned short* pk = (unsigned short*)(ws + 11336784);
  int*   bsum  = (int*)(ws + 11402320);
  int*   boff  = (int*)(ws + 11402576);

  // CSR build (runs every launch; ws is re-poisoned by the harness)
  k_prep<<<NZB + 64, 256, 0, stream>>>(ws + 9600000, W1, R1, Wc, Rc, pk);
  k_deg <<<(N_EDGES + 255) / 256, 256, 0, stream>>>(ei, deg);
  k_dinvsum<<<NB_SCAN, 256, 0, stream>>>(deg, dinv, bsum);
  k_bscan<<<1, 256, 0, stream>>>(bsum, boff, rowp);
  k_rowp<<<NB_SCAN, 256, 0, stream>>>(deg, boff, rowp);
  k_fill<<<(N_EDGES + 255) / 256, 256, 0, stream>>>(ei, rowp, cnt, dinv, csrc, enorm);

  const int NGB = (N_NODES + 63) / 64;    // 782
  const int NAB = (N_NODES + 7) / 8;      // 6250

  // layer 1 gemm: x (fp32) -> h0, skipb
  k_gemm0<<<NGB, 256, 0, stream>>>(x, pk + 0 * 16384, pk + 4 * 16384, b1, h0, skipb);
  // fused [agg1 + gemm2]: h0,skipb -> h1, skipb
  k_aggemm<false><<<NGB, 256, 0, stream>>>(h0, rowp, csrc, enorm,
      pk + 1 * 16384, pk + 5 * 16384, bc + 0 * DIM, h1, skipb, nullptr);
  // fused [agg2 + gemm3]: h1,skipb -> h0, skipb
  k_aggemm<false><<<NGB, 256, 0, stream>>>(h1, rowp, csrc, enorm,
      pk + 2 * 16384, pk + 6 * 16384, bc + 1 * DIM, h0, skipb, nullptr);
  // fused [agg3 + gemm4]: h0,skipb -> h1, dlast (fp32 skip)
  k_aggemm<true><<<NGB, 256, 0, stream>>>(h0, rowp, csrc, enorm,
      pk + 3 * 16384, pk + 7 * 16384, bc + 2 * DIM, h1, skipb, dlast);
  // final agg4: dlast = relu(dlast + gather(h1))
  k_aggF<<<NAB, 256, 0, stream>>>(h1, rowp, csrc, enorm, dlast);

  k_pool2<<<N_GRAPHS, 1024, 0, stream>>>(dlast, batch, pooled);
  k_mlp1<<<N_GRAPHS, 128, 0, stream>>>(pooled, l1w, l1b, g1);
  k_mlp2<<<1, N_GRAPHS, 0, stream>>>(g1, l2w, l2b, out);
}